// Round 6
// baseline (19584.557 us; speedup 1.0000x reference)
//
#include <hip/hip_runtime.h>
#include <hip/hip_bf16.h>
#include <math.h>

#define B_ 128
#define S_ 512
#define D_ 256
#define H_ 512
#define E_ 256
#define V_ 1002
#define T_ 34
#define END_ 1001
#define NWG_TOTAL 128
#define HROWB 1040   // LDS h-tile row stride: 512*2 + 16B pad (bank-spread)

typedef __attribute__((ext_vector_type(8))) short short8;
typedef __attribute__((ext_vector_type(4))) float f32x4;
typedef unsigned long long u64;

__device__ __forceinline__ float bf2f(unsigned short u){
  union { unsigned int i; float f; } x; x.i = ((unsigned int)u) << 16; return x.f;
}
__device__ __forceinline__ unsigned short f2bf(float f){
  union { float f; unsigned int i; } x; x.f = f;
  unsigned int r = x.i + 0x7fffu + ((x.i >> 16) & 1u);
  return (unsigned short)(r >> 16);
}
__device__ __forceinline__ float sigm(float x){ return 1.0f / (1.0f + expf(-x)); }

// write-through coherent store (reaches coherence point, never dirties L2)
__device__ __forceinline__ void store_coh8(unsigned short* p, u64 v){
  __hip_atomic_store((u64*)p, v, __ATOMIC_RELAXED, __HIP_MEMORY_SCOPE_AGENT);
}
__device__ __forceinline__ u64 load_coh8(const unsigned short* p){
  return __hip_atomic_load((const u64*)p, __ATOMIC_RELAXED, __HIP_MEMORY_SCOPE_AGENT);
}
__device__ __forceinline__ short8 load_coh16(const unsigned short* p){
  u64 lo = load_coh8(p);
  u64 hi = load_coh8(p + 4);
  union { u64 q[2]; short8 v; } u; u.q[0] = lo; u.q[1] = hi; return u.v;
}

// ---------------- conversion / setup kernels ----------------

__global__ void f2bf_kernel(const float* __restrict__ in, unsigned short* __restrict__ out, int n){
  int i = blockIdx.x * blockDim.x + threadIdx.x;
  int stride = gridDim.x * blockDim.x;
  for (; i < n; i += stride) out[i] = f2bf(in[i]);
}

__global__ void embed_kernel(const float* __restrict__ emb, const int* __restrict__ ids,
                             unsigned short* __restrict__ out){
  int i = blockIdx.x * blockDim.x + threadIdx.x;
  if (i >= B_ * T_ * E_) return;
  int bt = i >> 8;              // E_=256
  int e  = i & (E_ - 1);
  out[i] = f2bf(emb[(size_t)ids[bt] * E_ + e]);
}

// Wcat layout: [2048, K], K = Din + H. Row n = g*512 + j:
//   g=0 (r): [Wih_r | Whh_r]   g=1 (z): [Wih_z | Whh_z]
//   g=2 (n_input): [Wih_n | 0] g=3 (n_hidden): [0 | Whh_n]
__global__ void build_wcat(const float* __restrict__ Wih, const float* __restrict__ Whh,
                           unsigned short* __restrict__ Wcat, int Din){
  int K = Din + H_;
  int total = 2048 * K;
  int i = blockIdx.x * blockDim.x + threadIdx.x;
  int stride = gridDim.x * blockDim.x;
  for (; i < total; i += stride){
    int n = i / K, k = i - n * K;
    int g = n >> 9, j = n & 511;
    float v;
    if (g < 2){
      int r = (g << 9) + j;
      v = (k < Din) ? Wih[(size_t)r * Din + k] : Whh[(size_t)r * H_ + (k - Din)];
    } else if (g == 2){
      v = (k < Din) ? Wih[(size_t)(1024 + j) * Din + k] : 0.0f;
    } else {
      v = (k < Din) ? 0.0f : Whh[(size_t)(1024 + j) * H_ + (k - Din)];
    }
    Wcat[i] = f2bf(v);
  }
}

// bias4: [2048] = {bih_r+bhh_r, bih_z+bhh_z, bih_n, bhh_n}
__global__ void build_bias(const float* __restrict__ bih, const float* __restrict__ bhh,
                           float* __restrict__ out){
  int j = blockIdx.x * blockDim.x + threadIdx.x;
  if (j >= 512) return;
  out[j]        = bih[j] + bhh[j];
  out[512 + j]  = bih[512 + j] + bhh[512 + j];
  out[1024 + j] = bih[1024 + j];
  out[1536 + j] = bhh[1024 + j];
}

// ---------------- persistent RNN kernel ----------------
// 128 WGs x 256 threads. WGs 0..63: layer 0 (enc K=768 then dec K=768).
// WGs 64..127: layer 1 (K=1024), consuming y0/z0 via producer flag polls.
// Sync groups: (layer, mh) -> 32 WGs; flag-array (1 slot/WG), NO fences.
// Waves = K-quarters (all 4 gates x 16 cols each); weights VGPR-resident.
// h staged wave-contiguously into LDS each round via coherent u64 loads;
// L1 x-operand fragments loaded coherent direct-to-register; L0 x cached.
// Gate partials combined across waves via ds_add_f32 into 16KB LDS buffer.

template<int KT, int XKT, bool XCOH>
__device__ __forceinline__ void run_layer(
    char* smem,
    const unsigned short* __restrict__ Wc, const float* __restrict__ bias4,
    const unsigned short* __restrict__ Xbase, int x_rs, int x_ts,
    unsigned short* Ybase,                 // nullable; [t][128][512]
    unsigned short* hb0, unsigned short* hb1,
    int T, unsigned round0,
    unsigned* own_flags, int slot,
    unsigned* prod_flags, unsigned prod0,  // nullable
    u64* hprev,
    int jtile, int mh, int wv, int lane)
{
  constexpr int K = KT * 32;
  constexpr int KTL = KT / 4;          // kt-slices per wave
  const int tid  = threadIdx.x;
  const int ln   = lane & 15;
  const int lk8  = (lane >> 4) << 3;
  const int base_m = mh * 64;
  const int kt0 = wv * KTL;

  unsigned short* hA = (unsigned short*)smem;          // [64 rows][HROWB bytes]
  float* gbuf = (float*)(smem + 64 * HROWB);           // [4 gates][64][16] f32

  // ---- weights: 4 gates x 16 cols, K-slice [kt0*32, kt0*32+KTL*32) ----
  short8 wreg[4][KTL];
  #pragma unroll
  for (int g = 0; g < 4; ++g)
    #pragma unroll
    for (int k = 0; k < KTL; ++k)
      wreg[g][k] = *reinterpret_cast<const short8*>(
          Wc + (size_t)(g * 512 + jtile * 16 + ln) * K + (size_t)(kt0 + k) * 32 + lk8);

  // ---- epilogue ownership: thread = 1 row x 4 cols (one 8B h granule) ----
  const int erow  = tid >> 2;          // 0..63
  const int ecol0 = (tid & 3) << 2;    // 0,4,8,12
  const int ej    = (jtile << 4) + ecol0;
  const int egr   = base_m + erow;
  float br[4], bz[4], bni[4], bnh[4];
  #pragma unroll
  for (int c = 0; c < 4; ++c){
    br[c]  = bias4[ej + c];
    bz[c]  = bias4[512 + ej + c];
    bni[c] = bias4[1024 + ej + c];
    bnh[c] = bias4[1536 + ej + c];
  }

  const unsigned pidx = tid & 31;

  for (int t = 0; t < T; ++t){
    // ---- sync: own group (peers done reading prev h) + producer data ----
    if (wv == 0){
      const unsigned own_t  = round0 + (unsigned)t;
      const unsigned prod_t = prod0 + (unsigned)t + 1u;
      for (;;){
        unsigned f1 = __hip_atomic_load(own_flags + pidx, __ATOMIC_RELAXED, __HIP_MEMORY_SCOPE_AGENT);
        bool ok = (f1 >= own_t);
        if (prod_flags){
          unsigned f2 = __hip_atomic_load(prod_flags + pidx, __ATOMIC_RELAXED, __HIP_MEMORY_SCOPE_AGENT);
          ok = ok && (f2 >= prod_t);
        }
        if (__all(ok)) break;
        __builtin_amdgcn_s_sleep(1);
      }
    }
    __syncthreads();
    asm volatile("" ::: "memory");

    const unsigned short* Hin  = (t & 1) ? hb1 : hb0;
    unsigned short*       Hout = (t & 1) ? hb0 : hb1;
    const unsigned short* Xt   = Xbase + (size_t)t * x_ts;

    // ---- prefetch x-part fragments (overlaps with h staging latency) ----
    short8 afr[KTL][4];
    #pragma unroll
    for (int k = 0; k < KTL; ++k){
      const int kg = kt0 + k;
      if (kg < XKT){
        #pragma unroll
        for (int mt = 0; mt < 4; ++mt){
          const unsigned short* p = Xt + (size_t)(base_m + mt * 16 + ln) * x_rs + kg * 32 + lk8;
          afr[k][mt] = XCOH ? load_coh16(p) : *reinterpret_cast<const short8*>(p);
        }
      }
    }

    // ---- zero gate-partial buffer ----
    #pragma unroll
    for (int i = 0; i < 4; ++i)
      *reinterpret_cast<f32x4*>(gbuf + (size_t)(tid + i * 256) * 4) = (f32x4){0.f, 0.f, 0.f, 0.f};

    // ---- stage h tile (64KB) to LDS: wave-contiguous coherent u64 loads ----
    {
      const unsigned short* hsrc = Hin + ((size_t)base_m << 9);
      u64 sv[32];
      #pragma unroll
      for (int i = 0; i < 32; ++i)
        sv[i] = __hip_atomic_load((const u64*)hsrc + i * 256 + tid,
                                  __ATOMIC_RELAXED, __HIP_MEMORY_SCOPE_AGENT);
      #pragma unroll
      for (int i = 0; i < 32; ++i){
        const int idx = i * 256 + tid;             // u64 index; 128 per row
        *reinterpret_cast<u64*>((char*)hA + (idx >> 7) * HROWB + (idx & 127) * 8) = sv[i];
      }
    }
    __syncthreads();

    // ---- MFMA K-loop: 16 MFMAs per kt-slice (4 gates x 4 row-tiles) ----
    f32x4 acc[4][4];
    #pragma unroll
    for (int g = 0; g < 4; ++g)
      #pragma unroll
      for (int mt = 0; mt < 4; ++mt) acc[g][mt] = (f32x4){0.f, 0.f, 0.f, 0.f};

    #pragma unroll
    for (int k = 0; k < KTL; ++k){
      const int kg = kt0 + k;
      short8 a[4];
      if (kg < XKT){
        #pragma unroll
        for (int mt = 0; mt < 4; ++mt) a[mt] = afr[k][mt];
      } else {
        #pragma unroll
        for (int mt = 0; mt < 4; ++mt)
          a[mt] = *reinterpret_cast<const short8*>(
              (const char*)hA + (mt * 16 + ln) * HROWB + ((kg - XKT) * 32 + lk8) * 2);
      }
      #pragma unroll
      for (int g = 0; g < 4; ++g)
        #pragma unroll
        for (int mt = 0; mt < 4; ++mt)
          acc[g][mt] = __builtin_amdgcn_mfma_f32_16x16x32_bf16(a[mt], wreg[g][k], acc[g][mt], 0, 0, 0);
    }

    // ---- combine partial-K sums across waves (LDS f32 atomics) ----
    #pragma unroll
    for (int g = 0; g < 4; ++g)
      #pragma unroll
      for (int mt = 0; mt < 4; ++mt)
        #pragma unroll
        for (int r = 0; r < 4; ++r)
          atomicAdd(gbuf + g * 1024 + (mt * 16 + ((lane >> 4) << 2) + r) * 16 + ln,
                    acc[g][mt][r]);
    __syncthreads();

    // ---- epilogue: GRU nonlinearity; h-prev from register ----
    {
      f32x4 p0 = *reinterpret_cast<f32x4*>(gbuf +        erow * 16 + ecol0);
      f32x4 p1 = *reinterpret_cast<f32x4*>(gbuf + 1024 + erow * 16 + ecol0);
      f32x4 p2 = *reinterpret_cast<f32x4*>(gbuf + 2048 + erow * 16 + ecol0);
      f32x4 p3 = *reinterpret_cast<f32x4*>(gbuf + 3072 + erow * 16 + ecol0);
      u64 hv = *hprev;
      u64 hb = 0;
      #pragma unroll
      for (int c = 0; c < 4; ++c){
        float rr = sigm(p0[c] + br[c]);
        float zz = sigm(p1[c] + bz[c]);
        float nn = tanhf(p2[c] + bni[c] + rr * (p3[c] + bnh[c]));
        float hp = bf2f((unsigned short)(hv >> (16 * c)));
        float hn = (1.0f - zz) * nn + zz * hp;
        hb |= ((u64)f2bf(hn)) << (16 * c);
      }
      *hprev = hb;
      store_coh8(Hout + ((size_t)egr << 9) + ej, hb);
      if (Ybase)
        store_coh8(Ybase + (size_t)t * (B_ * H_) + ((size_t)egr << 9) + ej, hb);
    }

    // ---- publish: drain write-through stores, then flag my slot ----
    asm volatile("s_waitcnt vmcnt(0)" ::: "memory");
    __syncthreads();
    if (tid == 0)
      __hip_atomic_store(own_flags + slot, round0 + (unsigned)t + 1u,
                         __ATOMIC_RELAXED, __HIP_MEMORY_SCOPE_AGENT);
  }
}

__global__ __launch_bounds__(256, 1)
void rnn_persistent(
    const unsigned short* __restrict__ src, const unsigned short* __restrict__ tg,
    const unsigned short* __restrict__ Wc_e0, const unsigned short* __restrict__ Wc_e1,
    const unsigned short* __restrict__ Wc_d0, const unsigned short* __restrict__ Wc_d1,
    const float* __restrict__ b_e0, const float* __restrict__ b_e1,
    const float* __restrict__ b_d0, const float* __restrict__ b_d1,
    unsigned short* h0a, unsigned short* h0b,
    unsigned short* h1a, unsigned short* h1b,
    unsigned short* y0, unsigned short* z0, unsigned short* y1,
    unsigned* flags)
{
  __shared__ __align__(16) char smem[64 * HROWB + 16384];   // 81 KB: h tile + gate buf
  const int wg = blockIdx.x;
  const int layer = wg >> 6;
  const int gidx = wg & 63;
  const int jtile = gidx & 31, mh = gidx >> 5;
  const int wv = threadIdx.x >> 6, lane = threadIdx.x & 63;
  unsigned* own  = flags + (size_t)((layer << 1) | mh) * 64;
  unsigned* prod = flags + (size_t)mh * 64;     // layer-0 flags of same mh
  u64 hprev = 0;
  if (layer == 0){
    run_layer<24, 8, false>(smem, Wc_e0, b_e0, src, S_ * D_, D_, y0,
                            h0a, h0b, S_, 0u, own, jtile, nullptr, 0u, &hprev,
                            jtile, mh, wv, lane);
    run_layer<24, 8, false>(smem, Wc_d0, b_d0, tg, T_ * E_, E_, z0,
                            h0a, h0b, T_, 512u, own, jtile, nullptr, 0u, &hprev,
                            jtile, mh, wv, lane);
  } else {
    run_layer<32, 16, true>(smem, Wc_e1, b_e1, y0, H_, B_ * H_, (unsigned short*)nullptr,
                            h1a, h1b, S_, 0u, own, jtile, prod, 0u, &hprev,
                            jtile, mh, wv, lane);
    run_layer<32, 16, true>(smem, Wc_d1, b_d1, z0, H_, B_ * H_, y1,
                            h1a, h1b, T_, 512u, own, jtile, prod, 512u, &hprev,
                            jtile, mh, wv, lane);
  }
}

// ---------------- generic NT GEMM: C = act(A[M,K] @ W[N,K]^T + bias) ----------------
__global__ __launch_bounds__(256)
void gemm_nt(const unsigned short* __restrict__ A, const unsigned short* __restrict__ W,
             const float* __restrict__ bias,
             unsigned short* __restrict__ outB, float* __restrict__ outF,
             int M, int N, int K, int act)
{
  const int w    = threadIdx.x >> 6;
  const int lane = threadIdx.x & 63;
  const int ln   = lane & 15;
  const int lk8  = (lane >> 4) << 3;
  const int row0 = blockIdx.y * 32;
  const int col0 = blockIdx.x * 256 + w * 64;

  f32x4 acc[2][4];
  #pragma unroll
  for (int a = 0; a < 2; a++)
    #pragma unroll
    for (int g = 0; g < 4; g++) acc[a][g] = (f32x4){0.f, 0.f, 0.f, 0.f};

  const unsigned short* arow0 = A + (size_t)(row0 + ln) * K;
  const unsigned short* arow1 = A + (size_t)(row0 + 16 + ln) * K;
  const unsigned short* wrow[4];
  int ncol[4];
  #pragma unroll
  for (int nt = 0; nt < 4; ++nt){
    int n = col0 + nt * 16 + ln;
    ncol[nt] = n;
    int nc = n < N ? n : (N - 1);
    wrow[nt] = W + (size_t)nc * K;
  }

  const int nk = K >> 5;
  for (int kt = 0; kt < nk; ++kt){
    const int k = (kt << 5) + lk8;
    short8 a0 = *reinterpret_cast<const short8*>(arow0 + k);
    short8 a1 = *reinterpret_cast<const short8*>(arow1 + k);
    #pragma unroll
    for (int nt = 0; nt < 4; ++nt){
      short8 bf = *reinterpret_cast<const short8*>(wrow[nt] + k);
      acc[0][nt] = __builtin_amdgcn_mfma_f32_16x16x32_bf16(a0, bf, acc[0][nt], 0, 0, 0);
      acc[1][nt] = __builtin_amdgcn_mfma_f32_16x16x32_bf16(a1, bf, acc[1][nt], 0, 0, 0);
    }
  }

  #pragma unroll
  for (int nt = 0; nt < 4; ++nt){
    const int n = ncol[nt];
    if (n >= N) continue;
    const float bv = bias ? bias[n] : 0.0f;
    #pragma unroll
    for (int mt = 0; mt < 2; ++mt){
      const int rbase = row0 + mt * 16 + ((lane >> 4) << 2);
      #pragma unroll
      for (int reg = 0; reg < 4; ++reg){
        const int row = rbase + reg;
        if (row >= M) continue;
        float v = acc[mt][nt][reg] + bv;
        if (act == 1) v = sigm(v);
        if (outB) outB[(size_t)row * N + n] = f2bf(v);
        if (outF) outF[(size_t)row * N + n] = v;
      }
    }
  }
}

// ---------------- pooling + loss ----------------

// y1 layout: [T][B][H]
__global__ void pool_kernel(const unsigned short* __restrict__ y1, const int* __restrict__ lengths,
                            unsigned short* __restrict__ pooled){
  int i = blockIdx.x * blockDim.x + threadIdx.x;
  if (i >= B_ * H_) return;
  int b = i >> 9;              // H_=512
  int j = i & (H_ - 1);
  int len = lengths[b]; if (len > T_) len = T_;
  float s = 0.0f;
  for (int t = 0; t < len; ++t) s += bf2f(y1[((size_t)t * B_ + b) * H_ + j]);
  pooled[i] = f2bf(s);
}

__global__ void loss_kernel(const float* __restrict__ scores, float* __restrict__ out){
  __shared__ float wsum[4];
  const int w = threadIdx.x >> 6;
  const int lane = threadIdx.x & 63;
  float acc = 0.0f;
  for (int b = w; b < B_; b += 4){
    const float* row = scores + (size_t)b * V_;
    float vals[16];
    float mx = -1e30f;
    #pragma unroll
    for (int i = 0; i < 16; ++i){
      int c = lane + i * 64;
      vals[i] = (c < V_) ? row[c] : -1e30f;
      mx = fmaxf(mx, vals[i]);
    }
    #pragma unroll
    for (int off = 32; off; off >>= 1) mx = fmaxf(mx, __shfl_xor(mx, off));
    float se = 0.0f;
    #pragma unroll
    for (int i = 0; i < 16; ++i){
      int c = lane + i * 64;
      if (c < V_) se += expf(vals[i] - mx);
    }
    #pragma unroll
    for (int off = 32; off; off >>= 1) se += __shfl_xor(se, off);
    float logp = row[END_] - (mx + logf(se));
    acc += logp;
  }
  if (lane == 0) wsum[w] = acc;
  __syncthreads();
  if (threadIdx.x == 0){
    out[0] = -(wsum[0] + wsum[1] + wsum[2] + wsum[3]) / (float)B_;
  }
}

// ---------------- host orchestration ----------------

extern "C" void kernel_launch(void* const* d_in, const int* in_sizes, int n_in,
                              void* d_out, int out_size, void* d_ws, size_t ws_size,
                              hipStream_t stream) {
  const float* source   = (const float*)d_in[0];
  const int*   tgt_ids  = (const int*)  d_in[1];
  const int*   lengths  = (const int*)  d_in[2];
  const float* emb      = (const float*)d_in[3];
  const float* eWih0 = (const float*)d_in[4],  *eWhh0 = (const float*)d_in[5];
  const float* ebih0 = (const float*)d_in[6],  *ebhh0 = (const float*)d_in[7];
  const float* eWih1 = (const float*)d_in[8],  *eWhh1 = (const float*)d_in[9];
  const float* ebih1 = (const float*)d_in[10], *ebhh1 = (const float*)d_in[11];
  const float* dWih0 = (const float*)d_in[12], *dWhh0 = (const float*)d_in[13];
  const float* dbih0 = (const float*)d_in[14], *dbhh0 = (const float*)d_in[15];
  const float* dWih1 = (const float*)d_in[16], *dWhh1 = (const float*)d_in[17];
  const float* dbih1 = (const float*)d_in[18], *dbhh1 = (const float*)d_in[19];
  const float* fcW1 = (const float*)d_in[20], *fcb1 = (const float*)d_in[21];
  const float* fcW2 = (const float*)d_in[22], *fcb2 = (const float*)d_in[23];
  const float* fcW3 = (const float*)d_in[24], *fcb3 = (const float*)d_in[25];

  char* p = (char*)d_ws;
  auto alloc = [&](size_t bytes) -> void* {
    void* r = (void*)p;
    p += (bytes + 255) & ~(size_t)255;
    return r;
  };

  unsigned short* src_bf = (unsigned short*)alloc((size_t)B_ * S_ * D_ * 2);
  unsigned short* tg_bf  = (unsigned short*)alloc((size_t)B_ * T_ * E_ * 2);
  unsigned short* y0_bf  = (unsigned short*)alloc((size_t)S_ * B_ * H_ * 2);  // [t][b][h]
  unsigned short* z0d    = (unsigned short*)alloc((size_t)T_ * B_ * H_ * 2);  // [t][b][h]
  unsigned short* y1d    = (unsigned short*)alloc((size_t)T_ * B_ * H_ * 2);  // [t][b][h]
  unsigned short* h0a = (unsigned short*)alloc((size_t)B_ * H_ * 2);
  unsigned short* h0b = (unsigned short*)alloc((size_t)B_ * H_ * 2);
  unsigned short* h1a = (unsigned short*)alloc((size_t)B_ * H_ * 2);
  unsigned short* h1b = (unsigned short*)alloc((size_t)B_ * H_ * 2);
  unsigned short* Wc_e0 = (unsigned short*)alloc((size_t)2048 * 768  * 2);
  unsigned short* Wc_e1 = (unsigned short*)alloc((size_t)2048 * 1024 * 2);
  unsigned short* Wc_d0 = (unsigned short*)alloc((size_t)2048 * 768  * 2);
  unsigned short* Wc_d1 = (unsigned short*)alloc((size_t)2048 * 1024 * 2);
  float* bias_e0 = (float*)alloc(2048 * 4);
  float* bias_e1 = (float*)alloc(2048 * 4);
  float* bias_d0 = (float*)alloc(2048 * 4);
  float* bias_d1 = (float*)alloc(2048 * 4);
  unsigned short* fcW1b = (unsigned short*)alloc((size_t)2560 * 512  * 2);
  unsigned short* fcW2b = (unsigned short*)alloc((size_t)1024 * 2560 * 2);
  unsigned short* fcW3b = (unsigned short*)alloc((size_t)V_ * 1024 * 2);
  unsigned short* pooled = (unsigned short*)alloc((size_t)B_ * H_ * 2);
  unsigned short* x1_bf  = (unsigned short*)alloc((size_t)B_ * 2560 * 2);
  unsigned short* x2_bf  = (unsigned short*)alloc((size_t)B_ * 1024 * 2);
  float* scores = (float*)alloc((size_t)B_ * V_ * 4);
  unsigned* flags = (unsigned*)alloc(4 * 64 * 4);   // 4 groups x 64 u32 (256B stride)

  // --- setup / conversions ---
  f2bf_kernel<<<8192, 256, 0, stream>>>(source, src_bf, B_ * S_ * D_);
  embed_kernel<<<(B_ * T_ * E_ + 255) / 256, 256, 0, stream>>>(emb, tgt_ids, tg_bf);
  build_wcat<<<2048, 256, 0, stream>>>(eWih0, eWhh0, Wc_e0, D_);
  build_wcat<<<2048, 256, 0, stream>>>(eWih1, eWhh1, Wc_e1, H_);
  build_wcat<<<2048, 256, 0, stream>>>(dWih0, dWhh0, Wc_d0, E_);
  build_wcat<<<2048, 256, 0, stream>>>(dWih1, dWhh1, Wc_d1, H_);
  build_bias<<<2, 256, 0, stream>>>(ebih0, ebhh0, bias_e0);
  build_bias<<<2, 256, 0, stream>>>(ebih1, ebhh1, bias_e1);
  build_bias<<<2, 256, 0, stream>>>(dbih0, dbhh0, bias_d0);
  build_bias<<<2, 256, 0, stream>>>(dbih1, dbhh1, bias_d1);
  f2bf_kernel<<<4096, 256, 0, stream>>>(fcW1, fcW1b, 2560 * 512);
  f2bf_kernel<<<4096, 256, 0, stream>>>(fcW2, fcW2b, 1024 * 2560);
  f2bf_kernel<<<4096, 256, 0, stream>>>(fcW3, fcW3b, V_ * 1024);

  hipMemsetAsync(h0a, 0, (size_t)B_ * H_ * 2, stream);
  hipMemsetAsync(h0b, 0, (size_t)B_ * H_ * 2, stream);
  hipMemsetAsync(h1a, 0, (size_t)B_ * H_ * 2, stream);
  hipMemsetAsync(h1b, 0, (size_t)B_ * H_ * 2, stream);
  hipMemsetAsync(flags, 0, 4 * 64 * 4, stream);

  // --- persistent RNN: all 4 GRU layers, no cache-maintenance ops ---
  rnn_persistent<<<NWG_TOTAL, 256, 0, stream>>>(
      src_bf, tg_bf, Wc_e0, Wc_e1, Wc_d0, Wc_d1,
      bias_e0, bias_e1, bias_d0, bias_d1,
      h0a, h0b, h1a, h1b, y0_bf, z0d, y1d, flags);

  // --- masked time pooling ---
  pool_kernel<<<(B_ * H_ + 255) / 256, 256, 0, stream>>>(y1d, lengths, pooled);

  // --- FC chain ---
  {
    dim3 g1((2560 + 255) / 256, B_ / 32);
    gemm_nt<<<g1, 256, 0, stream>>>(pooled, fcW1b, fcb1, x1_bf, (float*)nullptr,
                                    B_, 2560, 512, 0);
    dim3 g2((1024 + 255) / 256, B_ / 32);
    gemm_nt<<<g2, 256, 0, stream>>>(x1_bf, fcW2b, fcb2, x2_bf, (float*)nullptr,
                                    B_, 1024, 2560, 0);
    dim3 g3((V_ + 255) / 256, B_ / 32);
    gemm_nt<<<g3, 256, 0, stream>>>(x2_bf, fcW3b, fcb3, (unsigned short*)nullptr, scores,
                                    B_, V_, 1024, 1);
  }

  // --- loss ---
  loss_kernel<<<1, 256, 0, stream>>>(scores, (float*)d_out);
}

// Round 7
// 5404.036 us; speedup vs baseline: 3.6241x; 3.6241x over previous
//
#include <hip/hip_runtime.h>
#include <hip/hip_bf16.h>
#include <math.h>

#define B_ 128
#define S_ 512
#define D_ 256
#define H_ 512
#define E_ 256
#define V_ 1002
#define T_ 34
#define END_ 1001
#define NWG_TOTAL 128
#define HROWB 1040   // LDS tile row pitch: 1024 B + 16 pad (2-way max bank alias)

typedef __attribute__((ext_vector_type(8))) short short8;
typedef __attribute__((ext_vector_type(4))) float f32x4;
typedef __attribute__((ext_vector_type(4))) int i32x4;
typedef unsigned long long u64;

__device__ __forceinline__ float bf2f(unsigned short u){
  union { unsigned int i; float f; } x; x.i = ((unsigned int)u) << 16; return x.f;
}
__device__ __forceinline__ unsigned short f2bf(float f){
  union { float f; unsigned int i; } x; x.f = f;
  unsigned int r = x.i + 0x7fffu + ((x.i >> 16) & 1u);
  return (unsigned short)(r >> 16);
}
__device__ __forceinline__ float sigm(float x){ return 1.0f / (1.0f + expf(-x)); }

// write-through coherent store (reaches coherence point, never dirties L2)
__device__ __forceinline__ void store_coh8(unsigned short* p, u64 v){
  __hip_atomic_store((u64*)p, v, __ATOMIC_RELAXED, __HIP_MEMORY_SCOPE_AGENT);
}

// stage a 64-row x 1024-B tile from global (coherence-point reads, 16B wide)
// into LDS with HROWB pitch. 256 threads; 16 passes of 4096 B.
// Volatile-asm ordering keeps the loads after the flag poll; the memory
// clobber on the waitcnt orders the LDS writes after load completion.
__device__ __forceinline__ void stage_tile(const unsigned short* src, char* dst, int tid){
  i32x4 r[16];
  #pragma unroll
  for (int p = 0; p < 16; ++p){
    const char* sp = (const char*)src + p * 4096 + tid * 16;
    asm volatile("global_load_dwordx4 %0, %1, off sc0 sc1" : "=v"(r[p]) : "v"(sp));
  }
  asm volatile("s_waitcnt vmcnt(0)" ::: "memory");
  #pragma unroll
  for (int p = 0; p < 16; ++p){
    const int off = p * 4096 + tid * 16;
    *reinterpret_cast<i32x4*>(dst + (off >> 10) * HROWB + (off & 1023)) = r[p];
  }
}

// ---------------- conversion / setup kernels ----------------

__global__ void f2bf_kernel(const float* __restrict__ in, unsigned short* __restrict__ out, int n){
  int i = blockIdx.x * blockDim.x + threadIdx.x;
  int stride = gridDim.x * blockDim.x;
  for (; i < n; i += stride) out[i] = f2bf(in[i]);
}

__global__ void embed_kernel(const float* __restrict__ emb, const int* __restrict__ ids,
                             unsigned short* __restrict__ out){
  int i = blockIdx.x * blockDim.x + threadIdx.x;
  if (i >= B_ * T_ * E_) return;
  int bt = i >> 8;              // E_=256
  int e  = i & (E_ - 1);
  out[i] = f2bf(emb[(size_t)ids[bt] * E_ + e]);
}

// Wcat layout: [2048, K], K = Din + H. Row n = g*512 + j:
//   g=0 (r): [Wih_r | Whh_r]   g=1 (z): [Wih_z | Whh_z]
//   g=2 (n_input): [Wih_n | 0] g=3 (n_hidden): [0 | Whh_n]
__global__ void build_wcat(const float* __restrict__ Wih, const float* __restrict__ Whh,
                           unsigned short* __restrict__ Wcat, int Din){
  int K = Din + H_;
  int total = 2048 * K;
  int i = blockIdx.x * blockDim.x + threadIdx.x;
  int stride = gridDim.x * blockDim.x;
  for (; i < total; i += stride){
    int n = i / K, k = i - n * K;
    int g = n >> 9, j = n & 511;
    float v;
    if (g < 2){
      int r = (g << 9) + j;
      v = (k < Din) ? Wih[(size_t)r * Din + k] : Whh[(size_t)r * H_ + (k - Din)];
    } else if (g == 2){
      v = (k < Din) ? Wih[(size_t)(1024 + j) * Din + k] : 0.0f;
    } else {
      v = (k < Din) ? 0.0f : Whh[(size_t)(1024 + j) * H_ + (k - Din)];
    }
    Wcat[i] = f2bf(v);
  }
}

// bias4: [2048] = {bih_r+bhh_r, bih_z+bhh_z, bih_n, bhh_n}
__global__ void build_bias(const float* __restrict__ bih, const float* __restrict__ bhh,
                           float* __restrict__ out){
  int j = blockIdx.x * blockDim.x + threadIdx.x;
  if (j >= 512) return;
  out[j]        = bih[j] + bhh[j];
  out[512 + j]  = bih[512 + j] + bhh[512 + j];
  out[1024 + j] = bih[1024 + j];
  out[1536 + j] = bhh[1024 + j];
}

// ---------------- persistent RNN kernel ----------------
// 128 WGs x 256 threads. WGs 0..63: layer 0 (enc K=768 then dec K=768).
// WGs 64..127: layer 1 (K=1024), consuming y0/z0 via producer flag polls.
// Sync groups: (layer, mh) -> 32 WGs; flag-array (1 slot/WG). NO cache
// maintenance ops anywhere: cross-WG stores are write-through coherent;
// cross-WG reads are 16B coherence-point loads staged into LDS per step.
// Read-only data (src/tg/weights/bias) stays normally cached and hot.
// Waves = gate chunks (r,z,n_in,n_hid); weights VGPR-resident per phase.
// h-prev carried in registers (each thread owns 1 row x 4 cols).

template<int KT, int XKT, bool XLDS>
__device__ __forceinline__ void run_layer(
    char* smem,
    const unsigned short* __restrict__ Wc, const float* __restrict__ bias4,
    const unsigned short* __restrict__ Xbase, int x_rs, int x_ts,
    unsigned short* Ybase,                 // nullable; [t][128][512]
    unsigned short* hb0, unsigned short* hb1,
    int T, unsigned round0,
    unsigned* own_flags, int slot,
    unsigned* prod_flags, unsigned prod0,  // nullable
    u64* hprev,
    int jtile, int mh, int wv, int lane)
{
  constexpr int K = KT * 32;
  const int tid  = threadIdx.x;
  const int ln   = lane & 15;
  const int lk8  = (lane >> 4) << 3;
  const int base_m = mh * 64;

  char* xA = smem;                          // L1: x tile rows 0..63
  char* hA = smem + (XLDS ? 64 * HROWB : 0);
  float* gbuf = (float*)(smem + 2 * 64 * HROWB);   // [4][64][17] f32

  // ---- weights: this wave's gate chunk, full K ----
  short8 wreg[KT];
  #pragma unroll
  for (int kt = 0; kt < KT; ++kt)
    wreg[kt] = *reinterpret_cast<const short8*>(
        Wc + (size_t)(wv * 512 + jtile * 16 + ln) * K + (size_t)kt * 32 + lk8);

  // ---- epilogue ownership: thread = 1 row x 4 cols (one 8B h granule) ----
  const int erow  = tid >> 2;          // 0..63
  const int ecol0 = (tid & 3) << 2;    // 0,4,8,12
  const int ej    = (jtile << 4) + ecol0;
  const int egr   = base_m + erow;
  float br[4], bz[4], bni[4], bnh[4];
  #pragma unroll
  for (int c = 0; c < 4; ++c){
    br[c]  = bias4[ej + c];
    bz[c]  = bias4[512 + ej + c];
    bni[c] = bias4[1024 + ej + c];
    bnh[c] = bias4[1536 + ej + c];
  }

  const unsigned pidx = tid & 31;

  for (int t = 0; t < T; ++t){
    // ---- sync: own group (peers done with step t-1) + producer data ----
    if (wv == 0){
      const unsigned own_t  = round0 + (unsigned)t;
      const unsigned prod_t = prod0 + (unsigned)t + 1u;
      for (;;){
        unsigned f1 = __hip_atomic_load(own_flags + pidx, __ATOMIC_RELAXED, __HIP_MEMORY_SCOPE_AGENT);
        bool ok = (f1 >= own_t);
        if (prod_flags){
          unsigned f2 = __hip_atomic_load(prod_flags + pidx, __ATOMIC_RELAXED, __HIP_MEMORY_SCOPE_AGENT);
          ok = ok && (f2 >= prod_t);
        }
        if (__all(ok)) break;
        __builtin_amdgcn_s_sleep(1);
      }
    }
    __syncthreads();

    const unsigned short* Hin  = (t & 1) ? hb1 : hb0;
    unsigned short*       Hout = (t & 1) ? hb0 : hb1;
    const unsigned short* Xt   = Xbase + (size_t)t * x_ts;

    // ---- stage dynamic operands to LDS (coherence-point 16B loads) ----
    if (XLDS) stage_tile(Xt + ((size_t)base_m << 9), xA, tid);
    stage_tile(Hin + ((size_t)base_m << 9), hA, tid);
    __syncthreads();

    // ---- MFMA K-loop: this wave's gate over full K ----
    f32x4 acc[4];
    #pragma unroll
    for (int mt = 0; mt < 4; ++mt) acc[mt] = (f32x4){0.f, 0.f, 0.f, 0.f};

    #pragma unroll
    for (int kt = 0; kt < KT; ++kt){
      short8 a[4];
      if (kt < XKT){
        if (XLDS){
          #pragma unroll
          for (int mt = 0; mt < 4; ++mt)
            a[mt] = *reinterpret_cast<const short8*>(
                xA + (mt * 16 + ln) * HROWB + (kt * 32 + lk8) * 2);
        } else {
          #pragma unroll
          for (int mt = 0; mt < 4; ++mt)
            a[mt] = *reinterpret_cast<const short8*>(
                Xt + (size_t)(base_m + mt * 16 + ln) * x_rs + kt * 32 + lk8);
        }
      } else {
        #pragma unroll
        for (int mt = 0; mt < 4; ++mt)
          a[mt] = *reinterpret_cast<const short8*>(
              hA + (mt * 16 + ln) * HROWB + ((kt - XKT) * 32 + lk8) * 2);
      }
      #pragma unroll
      for (int mt = 0; mt < 4; ++mt)
        acc[mt] = __builtin_amdgcn_mfma_f32_16x16x32_bf16(a[mt], wreg[kt], acc[mt], 0, 0, 0);
    }

    // ---- gate partials to LDS (each wave owns one gate, full K) ----
    #pragma unroll
    for (int mt = 0; mt < 4; ++mt){
      const int rl = mt * 16 + ((lane >> 4) << 2);
      #pragma unroll
      for (int i = 0; i < 4; ++i)
        gbuf[(wv * 64 + rl + i) * 17 + ln] = acc[mt][i];
    }
    __syncthreads();

    // ---- epilogue: GRU nonlinearity; h-prev from register ----
    {
      u64 hv = *hprev;
      u64 hb = 0;
      #pragma unroll
      for (int c = 0; c < 4; ++c){
        const int col = ecol0 + c;
        float p0 = gbuf[(      erow) * 17 + col];
        float p1 = gbuf[( 64 + erow) * 17 + col];
        float p2 = gbuf[(128 + erow) * 17 + col];
        float p3 = gbuf[(192 + erow) * 17 + col];
        float rr = sigm(p0 + br[c]);
        float zz = sigm(p1 + bz[c]);
        float nn = tanhf(p2 + bni[c] + rr * (p3 + bnh[c]));
        float hp = bf2f((unsigned short)(hv >> (16 * c)));
        float hn = (1.0f - zz) * nn + zz * hp;
        hb |= ((u64)f2bf(hn)) << (16 * c);
      }
      *hprev = hb;
      store_coh8(Hout + ((size_t)egr << 9) + ej, hb);
      if (Ybase)
        store_coh8(Ybase + (size_t)t * (B_ * H_) + ((size_t)egr << 9) + ej, hb);
    }

    // ---- publish: drain write-through stores, then flag my slot ----
    asm volatile("s_waitcnt vmcnt(0)" ::: "memory");
    __syncthreads();
    if (tid == 0)
      __hip_atomic_store(own_flags + slot, round0 + (unsigned)t + 1u,
                         __ATOMIC_RELAXED, __HIP_MEMORY_SCOPE_AGENT);
  }
}

__global__ __launch_bounds__(256, 1)
void rnn_persistent(
    const unsigned short* __restrict__ src, const unsigned short* __restrict__ tg,
    const unsigned short* __restrict__ Wc_e0, const unsigned short* __restrict__ Wc_e1,
    const unsigned short* __restrict__ Wc_d0, const unsigned short* __restrict__ Wc_d1,
    const float* __restrict__ b_e0, const float* __restrict__ b_e1,
    const float* __restrict__ b_d0, const float* __restrict__ b_d1,
    unsigned short* h0a, unsigned short* h0b,
    unsigned short* h1a, unsigned short* h1b,
    unsigned short* y0, unsigned short* z0, unsigned short* y1,
    unsigned* flags)
{
  // 2 tiles (x,h) * 64 rows * HROWB + gate buffer [4][64][17] f32
  __shared__ __align__(16) char smem[2 * 64 * HROWB + 4 * 64 * 17 * 4];
  const int wg = blockIdx.x;
  const int layer = wg >> 6;
  const int gidx = wg & 63;
  const int jtile = gidx & 31, mh = gidx >> 5;
  const int wv = threadIdx.x >> 6, lane = threadIdx.x & 63;
  unsigned* own  = flags + (size_t)((layer << 1) | mh) * 64;
  unsigned* prod = flags + (size_t)mh * 64;     // layer-0 flags of same mh
  u64 hprev = 0;
  if (layer == 0){
    run_layer<24, 8, false>(smem, Wc_e0, b_e0, src, S_ * D_, D_, y0,
                            h0a, h0b, S_, 0u, own, jtile, nullptr, 0u, &hprev,
                            jtile, mh, wv, lane);
    run_layer<24, 8, false>(smem, Wc_d0, b_d0, tg, T_ * E_, E_, z0,
                            h0a, h0b, T_, 512u, own, jtile, nullptr, 0u, &hprev,
                            jtile, mh, wv, lane);
  } else {
    run_layer<32, 16, true>(smem, Wc_e1, b_e1, y0, H_, B_ * H_, (unsigned short*)nullptr,
                            h1a, h1b, S_, 0u, own, jtile, prod, 0u, &hprev,
                            jtile, mh, wv, lane);
    run_layer<32, 16, true>(smem, Wc_d1, b_d1, z0, H_, B_ * H_, y1,
                            h1a, h1b, T_, 512u, own, jtile, prod, 512u, &hprev,
                            jtile, mh, wv, lane);
  }
}

// ---------------- generic NT GEMM: C = act(A[M,K] @ W[N,K]^T + bias) ----------------
__global__ __launch_bounds__(256)
void gemm_nt(const unsigned short* __restrict__ A, const unsigned short* __restrict__ W,
             const float* __restrict__ bias,
             unsigned short* __restrict__ outB, float* __restrict__ outF,
             int M, int N, int K, int act)
{
  const int w    = threadIdx.x >> 6;
  const int lane = threadIdx.x & 63;
  const int ln   = lane & 15;
  const int lk8  = (lane >> 4) << 3;
  const int row0 = blockIdx.y * 32;
  const int col0 = blockIdx.x * 256 + w * 64;

  f32x4 acc[2][4];
  #pragma unroll
  for (int a = 0; a < 2; a++)
    #pragma unroll
    for (int g = 0; g < 4; g++) acc[a][g] = (f32x4){0.f, 0.f, 0.f, 0.f};

  const unsigned short* arow0 = A + (size_t)(row0 + ln) * K;
  const unsigned short* arow1 = A + (size_t)(row0 + 16 + ln) * K;
  const unsigned short* wrow[4];
  int ncol[4];
  #pragma unroll
  for (int nt = 0; nt < 4; ++nt){
    int n = col0 + nt * 16 + ln;
    ncol[nt] = n;
    int nc = n < N ? n : (N - 1);
    wrow[nt] = W + (size_t)nc * K;
  }

  const int nk = K >> 5;
  for (int kt = 0; kt < nk; ++kt){
    const int k = (kt << 5) + lk8;
    short8 a0 = *reinterpret_cast<const short8*>(arow0 + k);
    short8 a1 = *reinterpret_cast<const short8*>(arow1 + k);
    #pragma unroll
    for (int nt = 0; nt < 4; ++nt){
      short8 bf = *reinterpret_cast<const short8*>(wrow[nt] + k);
      acc[0][nt] = __builtin_amdgcn_mfma_f32_16x16x32_bf16(a0, bf, acc[0][nt], 0, 0, 0);
      acc[1][nt] = __builtin_amdgcn_mfma_f32_16x16x32_bf16(a1, bf, acc[1][nt], 0, 0, 0);
    }
  }

  #pragma unroll
  for (int nt = 0; nt < 4; ++nt){
    const int n = ncol[nt];
    if (n >= N) continue;
    const float bv = bias ? bias[n] : 0.0f;
    #pragma unroll
    for (int mt = 0; mt < 2; ++mt){
      const int rbase = row0 + mt * 16 + ((lane >> 4) << 2);
      #pragma unroll
      for (int reg = 0; reg < 4; ++reg){
        const int row = rbase + reg;
        if (row >= M) continue;
        float v = acc[mt][nt][reg] + bv;
        if (act == 1) v = sigm(v);
        if (outB) outB[(size_t)row * N + n] = f2bf(v);
        if (outF) outF[(size_t)row * N + n] = v;
      }
    }
  }
}

// ---------------- pooling + loss ----------------

// y1 layout: [T][B][H]
__global__ void pool_kernel(const unsigned short* __restrict__ y1, const int* __restrict__ lengths,
                            unsigned short* __restrict__ pooled){
  int i = blockIdx.x * blockDim.x + threadIdx.x;
  if (i >= B_ * H_) return;
  int b = i >> 9;              // H_=512
  int j = i & (H_ - 1);
  int len = lengths[b]; if (len > T_) len = T_;
  float s = 0.0f;
  for (int t = 0; t < len; ++t) s += bf2f(y1[((size_t)t * B_ + b) * H_ + j]);
  pooled[i] = f2bf(s);
}

__global__ void loss_kernel(const float* __restrict__ scores, float* __restrict__ out){
  __shared__ float wsum[4];
  const int w = threadIdx.x >> 6;
  const int lane = threadIdx.x & 63;
  float acc = 0.0f;
  for (int b = w; b < B_; b += 4){
    const float* row = scores + (size_t)b * V_;
    float vals[16];
    float mx = -1e30f;
    #pragma unroll
    for (int i = 0; i < 16; ++i){
      int c = lane + i * 64;
      vals[i] = (c < V_) ? row[c] : -1e30f;
      mx = fmaxf(mx, vals[i]);
    }
    #pragma unroll
    for (int off = 32; off; off >>= 1) mx = fmaxf(mx, __shfl_xor(mx, off));
    float se = 0.0f;
    #pragma unroll
    for (int i = 0; i < 16; ++i){
      int c = lane + i * 64;
      if (c < V_) se += expf(vals[i] - mx);
    }
    #pragma unroll
    for (int off = 32; off; off >>= 1) se += __shfl_xor(se, off);
    float logp = row[END_] - (mx + logf(se));
    acc += logp;
  }
  if (lane == 0) wsum[w] = acc;
  __syncthreads();
  if (threadIdx.x == 0){
    out[0] = -(wsum[0] + wsum[1] + wsum[2] + wsum[3]) / (float)B_;
  }
}

// ---------------- host orchestration ----------------

extern "C" void kernel_launch(void* const* d_in, const int* in_sizes, int n_in,
                              void* d_out, int out_size, void* d_ws, size_t ws_size,
                              hipStream_t stream) {
  const float* source   = (const float*)d_in[0];
  const int*   tgt_ids  = (const int*)  d_in[1];
  const int*   lengths  = (const int*)  d_in[2];
  const float* emb      = (const float*)d_in[3];
  const float* eWih0 = (const float*)d_in[4],  *eWhh0 = (const float*)d_in[5];
  const float* ebih0 = (const float*)d_in[6],  *ebhh0 = (const float*)d_in[7];
  const float* eWih1 = (const float*)d_in[8],  *eWhh1 = (const float*)d_in[9];
  const float* ebih1 = (const float*)d_in[10], *ebhh1 = (const float*)d_in[11];
  const float* dWih0 = (const float*)d_in[12], *dWhh0 = (const float*)d_in[13];
  const float* dbih0 = (const float*)d_in[14], *dbhh0 = (const float*)d_in[15];
  const float* dWih1 = (const float*)d_in[16], *dWhh1 = (const float*)d_in[17];
  const float* dbih1 = (const float*)d_in[18], *dbhh1 = (const float*)d_in[19];
  const float* fcW1 = (const float*)d_in[20], *fcb1 = (const float*)d_in[21];
  const float* fcW2 = (const float*)d_in[22], *fcb2 = (const float*)d_in[23];
  const float* fcW3 = (const float*)d_in[24], *fcb3 = (const float*)d_in[25];

  char* p = (char*)d_ws;
  auto alloc = [&](size_t bytes) -> void* {
    void* r = (void*)p;
    p += (bytes + 255) & ~(size_t)255;
    return r;
  };

  unsigned short* src_bf = (unsigned short*)alloc((size_t)B_ * S_ * D_ * 2);
  unsigned short* tg_bf  = (unsigned short*)alloc((size_t)B_ * T_ * E_ * 2);
  unsigned short* y0_bf  = (unsigned short*)alloc((size_t)S_ * B_ * H_ * 2);  // [t][b][h]
  unsigned short* z0d    = (unsigned short*)alloc((size_t)T_ * B_ * H_ * 2);  // [t][b][h]
  unsigned short* y1d    = (unsigned short*)alloc((size_t)T_ * B_ * H_ * 2);  // [t][b][h]
  unsigned short* h0a = (unsigned short*)alloc((size_t)B_ * H_ * 2);
  unsigned short* h0b = (unsigned short*)alloc((size_t)B_ * H_ * 2);
  unsigned short* h1a = (unsigned short*)alloc((size_t)B_ * H_ * 2);
  unsigned short* h1b = (unsigned short*)alloc((size_t)B_ * H_ * 2);
  unsigned short* Wc_e0 = (unsigned short*)alloc((size_t)2048 * 768  * 2);
  unsigned short* Wc_e1 = (unsigned short*)alloc((size_t)2048 * 1024 * 2);
  unsigned short* Wc_d0 = (unsigned short*)alloc((size_t)2048 * 768  * 2);
  unsigned short* Wc_d1 = (unsigned short*)alloc((size_t)2048 * 1024 * 2);
  float* bias_e0 = (float*)alloc(2048 * 4);
  float* bias_e1 = (float*)alloc(2048 * 4);
  float* bias_d0 = (float*)alloc(2048 * 4);
  float* bias_d1 = (float*)alloc(2048 * 4);
  unsigned short* fcW1b = (unsigned short*)alloc((size_t)2560 * 512  * 2);
  unsigned short* fcW2b = (unsigned short*)alloc((size_t)1024 * 2560 * 2);
  unsigned short* fcW3b = (unsigned short*)alloc((size_t)V_ * 1024 * 2);
  unsigned short* pooled = (unsigned short*)alloc((size_t)B_ * H_ * 2);
  unsigned short* x1_bf  = (unsigned short*)alloc((size_t)B_ * 2560 * 2);
  unsigned short* x2_bf  = (unsigned short*)alloc((size_t)B_ * 1024 * 2);
  float* scores = (float*)alloc((size_t)B_ * V_ * 4);
  unsigned* flags = (unsigned*)alloc(4 * 64 * 4);   // 4 groups x 64 u32 (256B stride)

  // --- setup / conversions ---
  f2bf_kernel<<<8192, 256, 0, stream>>>(source, src_bf, B_ * S_ * D_);
  embed_kernel<<<(B_ * T_ * E_ + 255) / 256, 256, 0, stream>>>(emb, tgt_ids, tg_bf);
  build_wcat<<<2048, 256, 0, stream>>>(eWih0, eWhh0, Wc_e0, D_);
  build_wcat<<<2048, 256, 0, stream>>>(eWih1, eWhh1, Wc_e1, H_);
  build_wcat<<<2048, 256, 0, stream>>>(dWih0, dWhh0, Wc_d0, E_);
  build_wcat<<<2048, 256, 0, stream>>>(dWih1, dWhh1, Wc_d1, H_);
  build_bias<<<2, 256, 0, stream>>>(ebih0, ebhh0, bias_e0);
  build_bias<<<2, 256, 0, stream>>>(ebih1, ebhh1, bias_e1);
  build_bias<<<2, 256, 0, stream>>>(dbih0, dbhh0, bias_d0);
  build_bias<<<2, 256, 0, stream>>>(dbih1, dbhh1, bias_d1);
  f2bf_kernel<<<4096, 256, 0, stream>>>(fcW1, fcW1b, 2560 * 512);
  f2bf_kernel<<<4096, 256, 0, stream>>>(fcW2, fcW2b, 1024 * 2560);
  f2bf_kernel<<<4096, 256, 0, stream>>>(fcW3, fcW3b, V_ * 1024);

  hipMemsetAsync(h0a, 0, (size_t)B_ * H_ * 2, stream);
  hipMemsetAsync(h0b, 0, (size_t)B_ * H_ * 2, stream);
  hipMemsetAsync(h1a, 0, (size_t)B_ * H_ * 2, stream);
  hipMemsetAsync(h1b, 0, (size_t)B_ * H_ * 2, stream);
  hipMemsetAsync(flags, 0, 4 * 64 * 4, stream);

  // --- persistent RNN: all 4 GRU layers, fence-free, LDS-staged operands ---
  rnn_persistent<<<NWG_TOTAL, 256, 0, stream>>>(
      src_bf, tg_bf, Wc_e0, Wc_e1, Wc_d0, Wc_d1,
      bias_e0, bias_e1, bias_d0, bias_d1,
      h0a, h0b, h1a, h1b, y0_bf, z0d, y1d, flags);

  // --- masked time pooling ---
  pool_kernel<<<(B_ * H_ + 255) / 256, 256, 0, stream>>>(y1d, lengths, pooled);

  // --- FC chain ---
  {
    dim3 g1((2560 + 255) / 256, B_ / 32);
    gemm_nt<<<g1, 256, 0, stream>>>(pooled, fcW1b, fcb1, x1_bf, (float*)nullptr,
                                    B_, 2560, 512, 0);
    dim3 g2((1024 + 255) / 256, B_ / 32);
    gemm_nt<<<g2, 256, 0, stream>>>(x1_bf, fcW2b, fcb2, x2_bf, (float*)nullptr,
                                    B_, 1024, 2560, 0);
    dim3 g3((V_ + 255) / 256, B_ / 32);
    gemm_nt<<<g3, 256, 0, stream>>>(x2_bf, fcW3b, fcb3, (unsigned short*)nullptr, scores,
                                    B_, V_, 1024, 1);
  }

  // --- loss ---
  loss_kernel<<<1, 256, 0, stream>>>(scores, (float*)d_out);
}

// Round 8
// 5368.217 us; speedup vs baseline: 3.6482x; 1.0067x over previous
//
#include <hip/hip_runtime.h>
#include <hip/hip_bf16.h>
#include <math.h>

#define B_ 128
#define S_ 512
#define D_ 256
#define H_ 512
#define E_ 256
#define V_ 1002
#define T_ 34
#define END_ 1001
#define NWG_TOTAL 128
#define HROWB 1040   // LDS tile row pitch: 1024 B + 16 pad (2-way max bank alias)

typedef __attribute__((ext_vector_type(8))) short short8;
typedef __attribute__((ext_vector_type(4))) float f32x4;
typedef __attribute__((ext_vector_type(4))) int i32x4;
typedef unsigned long long u64;

__device__ __forceinline__ float bf2f(unsigned short u){
  union { unsigned int i; float f; } x; x.i = ((unsigned int)u) << 16; return x.f;
}
__device__ __forceinline__ unsigned short f2bf(float f){
  union { float f; unsigned int i; } x; x.f = f;
  unsigned int r = x.i + 0x7fffu + ((x.i >> 16) & 1u);
  return (unsigned short)(r >> 16);
}
__device__ __forceinline__ float sigm(float x){ return 1.0f / (1.0f + expf(-x)); }

// write-through coherent store (reaches coherence point, never dirties L2)
__device__ __forceinline__ void store_coh8(unsigned short* p, u64 v){
  __hip_atomic_store((u64*)p, v, __ATOMIC_RELAXED, __HIP_MEMORY_SCOPE_AGENT);
}

// wide coherent flag read: one 16B MALL load (coalesces across lanes)
__device__ __forceinline__ i32x4 load_flags16(const unsigned* p){
  i32x4 r;
  asm volatile("global_load_dwordx4 %0, %1, off sc0 sc1\n\ts_waitcnt vmcnt(0)"
               : "=v"(r) : "v"(p) : "memory");
  return r;
}

// stage a 64-row x 1024-B tile from global into LDS (HROWB pitch).
// COH: coherence-point (MALL) reads for rewritten data (h ping-pong).
// !COH: normal cached reads for write-once data (y0/z0) - L2-hit after
// the first toucher per XCD; freshness guaranteed because first touch
// happens strictly after the producer flag within this launch.
template<bool COH>
__device__ __forceinline__ void stage_tile(const unsigned short* src, char* dst, int tid){
  i32x4 r[16];
  #pragma unroll
  for (int p = 0; p < 16; ++p){
    const char* sp = (const char*)src + p * 4096 + tid * 16;
    if constexpr (COH)
      asm volatile("global_load_dwordx4 %0, %1, off sc0 sc1" : "=v"(r[p]) : "v"(sp));
    else
      asm volatile("global_load_dwordx4 %0, %1, off" : "=v"(r[p]) : "v"(sp));
  }
  asm volatile("s_waitcnt vmcnt(0)" ::: "memory");
  #pragma unroll
  for (int p = 0; p < 16; ++p){
    const int off = p * 4096 + tid * 16;
    *reinterpret_cast<i32x4*>(dst + (off >> 10) * HROWB + (off & 1023)) = r[p];
  }
}

// ---------------- conversion / setup kernels ----------------

__global__ void f2bf_kernel(const float* __restrict__ in, unsigned short* __restrict__ out, int n){
  int i = blockIdx.x * blockDim.x + threadIdx.x;
  int stride = gridDim.x * blockDim.x;
  for (; i < n; i += stride) out[i] = f2bf(in[i]);
}

__global__ void embed_kernel(const float* __restrict__ emb, const int* __restrict__ ids,
                             unsigned short* __restrict__ out){
  int i = blockIdx.x * blockDim.x + threadIdx.x;
  if (i >= B_ * T_ * E_) return;
  int bt = i >> 8;              // E_=256
  int e  = i & (E_ - 1);
  out[i] = f2bf(emb[(size_t)ids[bt] * E_ + e]);
}

// Wcat layout: [2048, K], K = Din + H. Row n = g*512 + j:
//   g=0 (r): [Wih_r | Whh_r]   g=1 (z): [Wih_z | Whh_z]
//   g=2 (n_input): [Wih_n | 0] g=3 (n_hidden): [0 | Whh_n]
__global__ void build_wcat(const float* __restrict__ Wih, const float* __restrict__ Whh,
                           unsigned short* __restrict__ Wcat, int Din){
  int K = Din + H_;
  int total = 2048 * K;
  int i = blockIdx.x * blockDim.x + threadIdx.x;
  int stride = gridDim.x * blockDim.x;
  for (; i < total; i += stride){
    int n = i / K, k = i - n * K;
    int g = n >> 9, j = n & 511;
    float v;
    if (g < 2){
      int r = (g << 9) + j;
      v = (k < Din) ? Wih[(size_t)r * Din + k] : Whh[(size_t)r * H_ + (k - Din)];
    } else if (g == 2){
      v = (k < Din) ? Wih[(size_t)(1024 + j) * Din + k] : 0.0f;
    } else {
      v = (k < Din) ? 0.0f : Whh[(size_t)(1024 + j) * H_ + (k - Din)];
    }
    Wcat[i] = f2bf(v);
  }
}

// bias4: [2048] = {bih_r+bhh_r, bih_z+bhh_z, bih_n, bhh_n}
__global__ void build_bias(const float* __restrict__ bih, const float* __restrict__ bhh,
                           float* __restrict__ out){
  int j = blockIdx.x * blockDim.x + threadIdx.x;
  if (j >= 512) return;
  out[j]        = bih[j] + bhh[j];
  out[512 + j]  = bih[512 + j] + bhh[512 + j];
  out[1024 + j] = bih[1024 + j];
  out[1536 + j] = bhh[1024 + j];
}

// ---------------- persistent RNN kernel ----------------
// 128 WGs x 256 threads. WGs 0..63: layer 0 (enc K=768 then dec K=768).
// WGs 64..127: layer 1 (K=1024), consuming y0/z0 via producer flag polls.
// Sync groups: (layer, mh) -> 32 WGs; flag-array (1 slot/WG). NO cache
// maintenance in the loop: cross-WG stores are write-through coherent;
// h-tile reads are coherence-point (MALL); write-once x-tiles (y0/z0)
// are normal cached reads (first touch is post-flag => fresh).
// Waves = gate chunks (r,z,n_in,n_hid); weights VGPR-resident per phase.
// h-prev carried in registers (each thread owns 1 row x 4 cols).

template<int KT, int XKT, bool XLDS>
__device__ __forceinline__ void run_layer(
    char* smem,
    const unsigned short* __restrict__ Wc, const float* __restrict__ bias4,
    const unsigned short* __restrict__ Xbase, int x_rs, int x_ts,
    unsigned short* Ybase,                 // nullable; [t][128][512]
    unsigned short* hb0, unsigned short* hb1,
    int T, unsigned round0,
    unsigned* own_flags, int slot,
    unsigned* prod_flags, unsigned prod0,  // nullable
    u64* hprev,
    int jtile, int mh, int wv, int lane)
{
  constexpr int K = KT * 32;
  const int tid  = threadIdx.x;
  const int ln   = lane & 15;
  const int lk8  = (lane >> 4) << 3;
  const int base_m = mh * 64;

  char* xA = smem;                          // x tile rows 0..63 (XLDS only)
  char* hA = smem + 64 * HROWB;
  float* gbuf = (float*)(smem + 2 * 64 * HROWB);   // [4][64][17] f32

  // ---- weights: this wave's gate chunk, full K ----
  short8 wreg[KT];
  #pragma unroll
  for (int kt = 0; kt < KT; ++kt)
    wreg[kt] = *reinterpret_cast<const short8*>(
        Wc + (size_t)(wv * 512 + jtile * 16 + ln) * K + (size_t)kt * 32 + lk8);

  // ---- epilogue ownership: thread = 1 row x 4 cols (one 8B h granule) ----
  const int erow  = tid >> 2;          // 0..63
  const int ecol0 = (tid & 3) << 2;    // 0,4,8,12
  const int ej    = (jtile << 4) + ecol0;
  const int egr   = base_m + erow;
  float br[4], bz[4], bni[4], bnh[4];
  #pragma unroll
  for (int c = 0; c < 4; ++c){
    br[c]  = bias4[ej + c];
    bz[c]  = bias4[512 + ej + c];
    bni[c] = bias4[1024 + ej + c];
    bnh[c] = bias4[1536 + ej + c];
  }

  for (int t = 0; t < T; ++t){
    // ---- sync: own group (peers done with step t-1) + producer data ----
    if (wv == 0){
      const unsigned own_t  = round0 + (unsigned)t;
      const unsigned prod_t = prod0 + (unsigned)t + 1u;
      const unsigned* pofs = own_flags + (lane & 7) * 4;
      const unsigned* ppfs = prod_flags ? (prod_flags + (lane & 7) * 4) : nullptr;
      for (;;){
        i32x4 f = load_flags16(pofs);
        bool ok = (unsigned)f.x >= own_t && (unsigned)f.y >= own_t &&
                  (unsigned)f.z >= own_t && (unsigned)f.w >= own_t;
        if (ppfs){
          i32x4 g = load_flags16(ppfs);
          ok = ok && (unsigned)g.x >= prod_t && (unsigned)g.y >= prod_t &&
                     (unsigned)g.z >= prod_t && (unsigned)g.w >= prod_t;
        }
        if (__all(ok)) break;
        __builtin_amdgcn_s_sleep(2);
      }
    }
    __syncthreads();

    const unsigned short* Hin  = (t & 1) ? hb1 : hb0;
    unsigned short*       Hout = (t & 1) ? hb0 : hb1;
    const unsigned short* Xt   = Xbase + (size_t)t * x_ts;

    // ---- stage operands to LDS: x cached (write-once), h coherent ----
    if (XLDS) stage_tile<false>(Xt + ((size_t)base_m << 9), xA, tid);
    stage_tile<true>(Hin + ((size_t)base_m << 9), hA, tid);
    __syncthreads();

    // ---- MFMA K-loop: this wave's gate over full K ----
    f32x4 acc[4];
    #pragma unroll
    for (int mt = 0; mt < 4; ++mt) acc[mt] = (f32x4){0.f, 0.f, 0.f, 0.f};

    #pragma unroll
    for (int kt = 0; kt < KT; ++kt){
      short8 a[4];
      if (kt < XKT){
        if (XLDS){
          #pragma unroll
          for (int mt = 0; mt < 4; ++mt)
            a[mt] = *reinterpret_cast<const short8*>(
                xA + (mt * 16 + ln) * HROWB + (kt * 32 + lk8) * 2);
        } else {
          #pragma unroll
          for (int mt = 0; mt < 4; ++mt)
            a[mt] = *reinterpret_cast<const short8*>(
                Xt + (size_t)(base_m + mt * 16 + ln) * x_rs + kt * 32 + lk8);
        }
      } else {
        #pragma unroll
        for (int mt = 0; mt < 4; ++mt)
          a[mt] = *reinterpret_cast<const short8*>(
              hA + (mt * 16 + ln) * HROWB + ((kt - XKT) * 32 + lk8) * 2);
      }
      #pragma unroll
      for (int mt = 0; mt < 4; ++mt)
        acc[mt] = __builtin_amdgcn_mfma_f32_16x16x32_bf16(a[mt], wreg[kt], acc[mt], 0, 0, 0);
    }

    // ---- gate partials to LDS (each wave owns one gate, full K) ----
    #pragma unroll
    for (int mt = 0; mt < 4; ++mt){
      const int rl = mt * 16 + ((lane >> 4) << 2);
      #pragma unroll
      for (int i = 0; i < 4; ++i)
        gbuf[(wv * 64 + rl + i) * 17 + ln] = acc[mt][i];
    }
    __syncthreads();

    // ---- epilogue: GRU nonlinearity; h-prev from register ----
    {
      u64 hv = *hprev;
      u64 hb = 0;
      #pragma unroll
      for (int c = 0; c < 4; ++c){
        const int col = ecol0 + c;
        float p0 = gbuf[(      erow) * 17 + col];
        float p1 = gbuf[( 64 + erow) * 17 + col];
        float p2 = gbuf[(128 + erow) * 17 + col];
        float p3 = gbuf[(192 + erow) * 17 + col];
        float rr = sigm(p0 + br[c]);
        float zz = sigm(p1 + bz[c]);
        float nn = tanhf(p2 + bni[c] + rr * (p3 + bnh[c]));
        float hp = bf2f((unsigned short)(hv >> (16 * c)));
        float hn = (1.0f - zz) * nn + zz * hp;
        hb |= ((u64)f2bf(hn)) << (16 * c);
      }
      *hprev = hb;
      store_coh8(Hout + ((size_t)egr << 9) + ej, hb);
      if (Ybase)
        store_coh8(Ybase + (size_t)t * (B_ * H_) + ((size_t)egr << 9) + ej, hb);
    }

    // ---- publish: drain write-through stores, then flag my slot ----
    asm volatile("s_waitcnt vmcnt(0)" ::: "memory");
    __syncthreads();
    if (tid == 0)
      __hip_atomic_store(own_flags + slot, round0 + (unsigned)t + 1u,
                         __ATOMIC_RELAXED, __HIP_MEMORY_SCOPE_AGENT);
  }
}

__global__ __launch_bounds__(256, 1)
void rnn_persistent(
    const unsigned short* __restrict__ src, const unsigned short* __restrict__ tg,
    const unsigned short* __restrict__ Wc_e0, const unsigned short* __restrict__ Wc_e1,
    const unsigned short* __restrict__ Wc_d0, const unsigned short* __restrict__ Wc_d1,
    const float* __restrict__ b_e0, const float* __restrict__ b_e1,
    const float* __restrict__ b_d0, const float* __restrict__ b_d1,
    unsigned short* h0a, unsigned short* h0b,
    unsigned short* h1a, unsigned short* h1b,
    unsigned short* y0, unsigned short* z0, unsigned short* y1,
    unsigned* flags)
{
  // 2 tiles (x,h) * 64 rows * HROWB + gate buffer [4][64][17] f32
  __shared__ __align__(16) char smem[2 * 64 * HROWB + 4 * 64 * 17 * 4];
  // one-time acquire: clear poison / previous-replay lines from caches
  __builtin_amdgcn_fence(__ATOMIC_ACQUIRE, "agent");
  const int wg = blockIdx.x;
  const int layer = wg >> 6;
  const int gidx = wg & 63;
  const int jtile = gidx & 31, mh = gidx >> 5;
  const int wv = threadIdx.x >> 6, lane = threadIdx.x & 63;
  unsigned* own  = flags + (size_t)((layer << 1) | mh) * 64;
  unsigned* prod = flags + (size_t)mh * 64;     // layer-0 flags of same mh
  u64 hprev = 0;
  if (layer == 0){
    run_layer<24, 8, false>(smem, Wc_e0, b_e0, src, S_ * D_, D_, y0,
                            h0a, h0b, S_, 0u, own, jtile, nullptr, 0u, &hprev,
                            jtile, mh, wv, lane);
    run_layer<24, 8, false>(smem, Wc_d0, b_d0, tg, T_ * E_, E_, z0,
                            h0a, h0b, T_, 512u, own, jtile, nullptr, 0u, &hprev,
                            jtile, mh, wv, lane);
  } else {
    run_layer<32, 16, true>(smem, Wc_e1, b_e1, y0, H_, B_ * H_, (unsigned short*)nullptr,
                            h1a, h1b, S_, 0u, own, jtile, prod, 0u, &hprev,
                            jtile, mh, wv, lane);
    run_layer<32, 16, true>(smem, Wc_d1, b_d1, z0, H_, B_ * H_, y1,
                            h1a, h1b, T_, 512u, own, jtile, prod, 512u, &hprev,
                            jtile, mh, wv, lane);
  }
}

// ---------------- generic NT GEMM: C = act(A[M,K] @ W[N,K]^T + bias) ----------------
__global__ __launch_bounds__(256)
void gemm_nt(const unsigned short* __restrict__ A, const unsigned short* __restrict__ W,
             const float* __restrict__ bias,
             unsigned short* __restrict__ outB, float* __restrict__ outF,
             int M, int N, int K, int act)
{
  const int w    = threadIdx.x >> 6;
  const int lane = threadIdx.x & 63;
  const int ln   = lane & 15;
  const int lk8  = (lane >> 4) << 3;
  const int row0 = blockIdx.y * 32;
  const int col0 = blockIdx.x * 256 + w * 64;

  f32x4 acc[2][4];
  #pragma unroll
  for (int a = 0; a < 2; a++)
    #pragma unroll
    for (int g = 0; g < 4; g++) acc[a][g] = (f32x4){0.f, 0.f, 0.f, 0.f};

  const unsigned short* arow0 = A + (size_t)(row0 + ln) * K;
  const unsigned short* arow1 = A + (size_t)(row0 + 16 + ln) * K;
  const unsigned short* wrow[4];
  int ncol[4];
  #pragma unroll
  for (int nt = 0; nt < 4; ++nt){
    int n = col0 + nt * 16 + ln;
    ncol[nt] = n;
    int nc = n < N ? n : (N - 1);
    wrow[nt] = W + (size_t)nc * K;
  }

  const int nk = K >> 5;
  for (int kt = 0; kt < nk; ++kt){
    const int k = (kt << 5) + lk8;
    short8 a0 = *reinterpret_cast<const short8*>(arow0 + k);
    short8 a1 = *reinterpret_cast<const short8*>(arow1 + k);
    #pragma unroll
    for (int nt = 0; nt < 4; ++nt){
      short8 bf = *reinterpret_cast<const short8*>(wrow[nt] + k);
      acc[0][nt] = __builtin_amdgcn_mfma_f32_16x16x32_bf16(a0, bf, acc[0][nt], 0, 0, 0);
      acc[1][nt] = __builtin_amdgcn_mfma_f32_16x16x32_bf16(a1, bf, acc[1][nt], 0, 0, 0);
    }
  }

  #pragma unroll
  for (int nt = 0; nt < 4; ++nt){
    const int n = ncol[nt];
    if (n >= N) continue;
    const float bv = bias ? bias[n] : 0.0f;
    #pragma unroll
    for (int mt = 0; mt < 2; ++mt){
      const int rbase = row0 + mt * 16 + ((lane >> 4) << 2);
      #pragma unroll
      for (int reg = 0; reg < 4; ++reg){
        const int row = rbase + reg;
        if (row >= M) continue;
        float v = acc[mt][nt][reg] + bv;
        if (act == 1) v = sigm(v);
        if (outB) outB[(size_t)row * N + n] = f2bf(v);
        if (outF) outF[(size_t)row * N + n] = v;
      }
    }
  }
}

// ---------------- pooling + loss ----------------

// y1 layout: [T][B][H]
__global__ void pool_kernel(const unsigned short* __restrict__ y1, const int* __restrict__ lengths,
                            unsigned short* __restrict__ pooled){
  int i = blockIdx.x * blockDim.x + threadIdx.x;
  if (i >= B_ * H_) return;
  int b = i >> 9;              // H_=512
  int j = i & (H_ - 1);
  int len = lengths[b]; if (len > T_) len = T_;
  float s = 0.0f;
  for (int t = 0; t < len; ++t) s += bf2f(y1[((size_t)t * B_ + b) * H_ + j]);
  pooled[i] = f2bf(s);
}

__global__ void loss_kernel(const float* __restrict__ scores, float* __restrict__ out){
  __shared__ float wsum[4];
  const int w = threadIdx.x >> 6;
  const int lane = threadIdx.x & 63;
  float acc = 0.0f;
  for (int b = w; b < B_; b += 4){
    const float* row = scores + (size_t)b * V_;
    float vals[16];
    float mx = -1e30f;
    #pragma unroll
    for (int i = 0; i < 16; ++i){
      int c = lane + i * 64;
      vals[i] = (c < V_) ? row[c] : -1e30f;
      mx = fmaxf(mx, vals[i]);
    }
    #pragma unroll
    for (int off = 32; off; off >>= 1) mx = fmaxf(mx, __shfl_xor(mx, off));
    float se = 0.0f;
    #pragma unroll
    for (int i = 0; i < 16; ++i){
      int c = lane + i * 64;
      if (c < V_) se += expf(vals[i] - mx);
    }
    #pragma unroll
    for (int off = 32; off; off >>= 1) se += __shfl_xor(se, off);
    float logp = row[END_] - (mx + logf(se));
    acc += logp;
  }
  if (lane == 0) wsum[w] = acc;
  __syncthreads();
  if (threadIdx.x == 0){
    out[0] = -(wsum[0] + wsum[1] + wsum[2] + wsum[3]) / (float)B_;
  }
}

// ---------------- host orchestration ----------------

extern "C" void kernel_launch(void* const* d_in, const int* in_sizes, int n_in,
                              void* d_out, int out_size, void* d_ws, size_t ws_size,
                              hipStream_t stream) {
  const float* source   = (const float*)d_in[0];
  const int*   tgt_ids  = (const int*)  d_in[1];
  const int*   lengths  = (const int*)  d_in[2];
  const float* emb      = (const float*)d_in[3];
  const float* eWih0 = (const float*)d_in[4],  *eWhh0 = (const float*)d_in[5];
  const float* ebih0 = (const float*)d_in[6],  *ebhh0 = (const float*)d_in[7];
  const float* eWih1 = (const float*)d_in[8],  *eWhh1 = (const float*)d_in[9];
  const float* ebih1 = (const float*)d_in[10], *ebhh1 = (const float*)d_in[11];
  const float* dWih0 = (const float*)d_in[12], *dWhh0 = (const float*)d_in[13];
  const float* dbih0 = (const float*)d_in[14], *dbhh0 = (const float*)d_in[15];
  const float* dWih1 = (const float*)d_in[16], *dWhh1 = (const float*)d_in[17];
  const float* dbih1 = (const float*)d_in[18], *dbhh1 = (const float*)d_in[19];
  const float* fcW1 = (const float*)d_in[20], *fcb1 = (const float*)d_in[21];
  const float* fcW2 = (const float*)d_in[22], *fcb2 = (const float*)d_in[23];
  const float* fcW3 = (const float*)d_in[24], *fcb3 = (const float*)d_in[25];

  char* p = (char*)d_ws;
  auto alloc = [&](size_t bytes) -> void* {
    void* r = (void*)p;
    p += (bytes + 255) & ~(size_t)255;
    return r;
  };

  unsigned short* src_bf = (unsigned short*)alloc((size_t)B_ * S_ * D_ * 2);
  unsigned short* tg_bf  = (unsigned short*)alloc((size_t)B_ * T_ * E_ * 2);
  unsigned short* y0_bf  = (unsigned short*)alloc((size_t)S_ * B_ * H_ * 2);  // [t][b][h]
  unsigned short* z0d    = (unsigned short*)alloc((size_t)T_ * B_ * H_ * 2);  // [t][b][h]
  unsigned short* y1d    = (unsigned short*)alloc((size_t)T_ * B_ * H_ * 2);  // [t][b][h]
  unsigned short* h0a = (unsigned short*)alloc((size_t)B_ * H_ * 2);
  unsigned short* h0b = (unsigned short*)alloc((size_t)B_ * H_ * 2);
  unsigned short* h1a = (unsigned short*)alloc((size_t)B_ * H_ * 2);
  unsigned short* h1b = (unsigned short*)alloc((size_t)B_ * H_ * 2);
  unsigned short* Wc_e0 = (unsigned short*)alloc((size_t)2048 * 768  * 2);
  unsigned short* Wc_e1 = (unsigned short*)alloc((size_t)2048 * 1024 * 2);
  unsigned short* Wc_d0 = (unsigned short*)alloc((size_t)2048 * 768  * 2);
  unsigned short* Wc_d1 = (unsigned short*)alloc((size_t)2048 * 1024 * 2);
  float* bias_e0 = (float*)alloc(2048 * 4);
  float* bias_e1 = (float*)alloc(2048 * 4);
  float* bias_d0 = (float*)alloc(2048 * 4);
  float* bias_d1 = (float*)alloc(2048 * 4);
  unsigned short* fcW1b = (unsigned short*)alloc((size_t)2560 * 512  * 2);
  unsigned short* fcW2b = (unsigned short*)alloc((size_t)1024 * 2560 * 2);
  unsigned short* fcW3b = (unsigned short*)alloc((size_t)V_ * 1024 * 2);
  unsigned short* pooled = (unsigned short*)alloc((size_t)B_ * H_ * 2);
  unsigned short* x1_bf  = (unsigned short*)alloc((size_t)B_ * 2560 * 2);
  unsigned short* x2_bf  = (unsigned short*)alloc((size_t)B_ * 1024 * 2);
  float* scores = (float*)alloc((size_t)B_ * V_ * 4);
  unsigned* flags = (unsigned*)alloc(4 * 64 * 4);   // 4 groups x 64 u32 (256B stride)

  // --- setup / conversions ---
  f2bf_kernel<<<8192, 256, 0, stream>>>(source, src_bf, B_ * S_ * D_);
  embed_kernel<<<(B_ * T_ * E_ + 255) / 256, 256, 0, stream>>>(emb, tgt_ids, tg_bf);
  build_wcat<<<2048, 256, 0, stream>>>(eWih0, eWhh0, Wc_e0, D_);
  build_wcat<<<2048, 256, 0, stream>>>(eWih1, eWhh1, Wc_e1, H_);
  build_wcat<<<2048, 256, 0, stream>>>(dWih0, dWhh0, Wc_d0, E_);
  build_wcat<<<2048, 256, 0, stream>>>(dWih1, dWhh1, Wc_d1, H_);
  build_bias<<<2, 256, 0, stream>>>(ebih0, ebhh0, bias_e0);
  build_bias<<<2, 256, 0, stream>>>(ebih1, ebhh1, bias_e1);
  build_bias<<<2, 256, 0, stream>>>(dbih0, dbhh0, bias_d0);
  build_bias<<<2, 256, 0, stream>>>(dbih1, dbhh1, bias_d1);
  f2bf_kernel<<<4096, 256, 0, stream>>>(fcW1, fcW1b, 2560 * 512);
  f2bf_kernel<<<4096, 256, 0, stream>>>(fcW2, fcW2b, 1024 * 2560);
  f2bf_kernel<<<4096, 256, 0, stream>>>(fcW3, fcW3b, V_ * 1024);

  hipMemsetAsync(h0a, 0, (size_t)B_ * H_ * 2, stream);
  hipMemsetAsync(h0b, 0, (size_t)B_ * H_ * 2, stream);
  hipMemsetAsync(h1a, 0, (size_t)B_ * H_ * 2, stream);
  hipMemsetAsync(h1b, 0, (size_t)B_ * H_ * 2, stream);
  hipMemsetAsync(flags, 0, 4 * 64 * 4, stream);

  // --- persistent RNN: all 4 GRU layers ---
  rnn_persistent<<<NWG_TOTAL, 256, 0, stream>>>(
      src_bf, tg_bf, Wc_e0, Wc_e1, Wc_d0, Wc_d1,
      bias_e0, bias_e1, bias_d0, bias_d1,
      h0a, h0b, h1a, h1b, y0_bf, z0d, y1d, flags);

  // --- masked time pooling ---
  pool_kernel<<<(B_ * H_ + 255) / 256, 256, 0, stream>>>(y1d, lengths, pooled);

  // --- FC chain ---
  {
    dim3 g1((2560 + 255) / 256, B_ / 32);
    gemm_nt<<<g1, 256, 0, stream>>>(pooled, fcW1b, fcb1, x1_bf, (float*)nullptr,
                                    B_, 2560, 512, 0);
    dim3 g2((1024 + 255) / 256, B_ / 32);
    gemm_nt<<<g2, 256, 0, stream>>>(x1_bf, fcW2b, fcb2, x2_bf, (float*)nullptr,
                                    B_, 1024, 2560, 0);
    dim3 g3((V_ + 255) / 256, B_ / 32);
    gemm_nt<<<g3, 256, 0, stream>>>(x2_bf, fcW3b, fcb3, (unsigned short*)nullptr, scores,
                                    B_, V_, 1024, 1);
  }

  // --- loss ---
  loss_kernel<<<1, 256, 0, stream>>>(scores, (float*)d_out);
}

// Round 9
// 4386.632 us; speedup vs baseline: 4.4646x; 1.2238x over previous
//
#include <hip/hip_runtime.h>
#include <hip/hip_bf16.h>
#include <math.h>

#define B_ 128
#define S_ 512
#define D_ 256
#define H_ 512
#define E_ 256
#define V_ 1002
#define T_ 34
#define END_ 1001
#define NWG_TOTAL 128
#define HROWB 1040       // LDS h tile row pitch (bytes)
#define GPITCH 20        // gbuf row pitch (dwords), 80B: 16B-aligned, conflict-light

typedef __attribute__((ext_vector_type(8))) short short8;
typedef __attribute__((ext_vector_type(4))) float f32x4;
typedef __attribute__((ext_vector_type(4))) int i32x4;
typedef unsigned long long u64;

__device__ __forceinline__ float bf2f(unsigned short u){
  union { unsigned int i; float f; } x; x.i = ((unsigned int)u) << 16; return x.f;
}
__device__ __forceinline__ unsigned short f2bf(float f){
  union { float f; unsigned int i; } x; x.f = f;
  unsigned int r = x.i + 0x7fffu + ((x.i >> 16) & 1u);
  return (unsigned short)(r >> 16);
}
__device__ __forceinline__ float sigm(float x){ return 1.0f / (1.0f + expf(-x)); }

// write-through coherent store (reaches coherence point, never dirties L2)
__device__ __forceinline__ void store_coh8(unsigned short* p, u64 v){
  __hip_atomic_store((u64*)p, v, __ATOMIC_RELAXED, __HIP_MEMORY_SCOPE_AGENT);
}

// wide coherent flag read: one 16B MALL load (coalesces across lanes)
__device__ __forceinline__ i32x4 load_flags16(const unsigned* p){
  i32x4 r;
  asm volatile("global_load_dwordx4 %0, %1, off sc0 sc1\n\ts_waitcnt vmcnt(0)"
               : "=v"(r) : "v"(p) : "memory");
  return r;
}

// stage the 64-row x 1024-B h tile from global (coherence-point 16B reads)
// into LDS with HROWB pitch. 256 threads; 16 passes of 4096 B.
__device__ __forceinline__ void stage_tile_coh(const unsigned short* src, char* dst, int tid){
  i32x4 r[16];
  #pragma unroll
  for (int p = 0; p < 16; ++p){
    const char* sp = (const char*)src + p * 4096 + tid * 16;
    asm volatile("global_load_dwordx4 %0, %1, off sc0 sc1" : "=v"(r[p]) : "v"(sp));
  }
  asm volatile("s_waitcnt vmcnt(0)" ::: "memory");
  #pragma unroll
  for (int p = 0; p < 16; ++p){
    const int off = p * 4096 + tid * 16;
    *reinterpret_cast<i32x4*>(dst + (off >> 10) * HROWB + (off & 1023)) = r[p];
  }
}

// ---------------- conversion / setup kernels ----------------

__global__ void f2bf_kernel(const float* __restrict__ in, unsigned short* __restrict__ out, int n){
  int i = blockIdx.x * blockDim.x + threadIdx.x;
  int stride = gridDim.x * blockDim.x;
  for (; i < n; i += stride) out[i] = f2bf(in[i]);
}

__global__ void embed_kernel(const float* __restrict__ emb, const int* __restrict__ ids,
                             unsigned short* __restrict__ out){
  int i = blockIdx.x * blockDim.x + threadIdx.x;
  if (i >= B_ * T_ * E_) return;
  int bt = i >> 8;              // E_=256
  int e  = i & (E_ - 1);
  out[i] = f2bf(emb[(size_t)ids[bt] * E_ + e]);
}

// Wcat layout: [2048, K], K = Din + H. Row n = g*512 + j:
//   g=0 (r): [Wih_r | Whh_r]   g=1 (z): [Wih_z | Whh_z]
//   g=2 (n_input): [Wih_n | 0] g=3 (n_hidden): [0 | Whh_n]
__global__ void build_wcat(const float* __restrict__ Wih, const float* __restrict__ Whh,
                           unsigned short* __restrict__ Wcat, int Din){
  int K = Din + H_;
  int total = 2048 * K;
  int i = blockIdx.x * blockDim.x + threadIdx.x;
  int stride = gridDim.x * blockDim.x;
  for (; i < total; i += stride){
    int n = i / K, k = i - n * K;
    int g = n >> 9, j = n & 511;
    float v;
    if (g < 2){
      int r = (g << 9) + j;
      v = (k < Din) ? Wih[(size_t)r * Din + k] : Whh[(size_t)r * H_ + (k - Din)];
    } else if (g == 2){
      v = (k < Din) ? Wih[(size_t)(1024 + j) * Din + k] : 0.0f;
    } else {
      v = (k < Din) ? 0.0f : Whh[(size_t)(1024 + j) * H_ + (k - Din)];
    }
    Wcat[i] = f2bf(v);
  }
}

// bias4: [2048] = {bih_r+bhh_r, bih_z+bhh_z, bih_n, bhh_n}
__global__ void build_bias(const float* __restrict__ bih, const float* __restrict__ bhh,
                           float* __restrict__ out){
  int j = blockIdx.x * blockDim.x + threadIdx.x;
  if (j >= 512) return;
  out[j]        = bih[j] + bhh[j];
  out[512 + j]  = bih[512 + j] + bhh[512 + j];
  out[1024 + j] = bih[1024 + j];
  out[1536 + j] = bhh[1024 + j];
}

// ---------------- persistent RNN kernel ----------------
// 128 WGs x 256 threads. WGs 0..63: layer 0 (enc K=768 then dec K=768).
// WGs 64..127: layer 1 (K=1024), consuming y0/z0 via producer flag polls.
// Sync groups: (layer, mh) -> 32 WGs; flag-array (1 slot/WG). No cache
// maintenance in the loop: cross-WG stores write-through coherent; h-tile
// staged via coherence-point 16B loads; write-once x (src/tg/y0/z0) read
// directly from CACHED global inside the K-loop (fresh: first touch is
// post-flag; entry acquire-fence cleared stale lines from prior replays).
// Waves = K-quarters x ALL 4 gates: each A-fragment read once from LDS
// (4x less LDS traffic than gate-split waves). Cross-wave K-reduction via
// two-pass gbuf[q][4g][64][GPITCH]. Weights VGPR-resident per phase.
// h-prev carried in registers (each thread owns 1 row x 4 cols).

template<int KT, int XKT>
__device__ __forceinline__ void run_layer(
    char* smem,
    const unsigned short* __restrict__ Wc, const float* __restrict__ bias4,
    const unsigned short* __restrict__ Xbase, int x_rs, int x_ts,
    unsigned short* Ybase,                 // nullable; [t][128][512]
    unsigned short* hb0, unsigned short* hb1,
    int T, unsigned round0,
    unsigned* own_flags, int slot,
    unsigned* prod_flags, unsigned prod0,  // nullable
    u64* hprev,
    int jtile, int mh, int wv, int lane)
{
  constexpr int K   = KT * 32;
  constexpr int KTL = KT / 4;          // kt-slices per wave
  const int tid  = threadIdx.x;
  const int ln   = lane & 15;
  const int lk8  = (lane >> 4) << 3;
  const int base_m = mh * 64;
  const int q = wv;                    // this wave's K-quarter

  char*  hA   = smem;                                   // [64][HROWB]
  float* gbuf = (float*)(smem + 64 * HROWB);            // [4q][4g][64][GPITCH]

  // ---- weights: 4 gates x 16 cols, K-slice [q*KTL*32, ...) ----
  short8 wreg[4][KTL];
  #pragma unroll
  for (int g = 0; g < 4; ++g)
    #pragma unroll
    for (int k = 0; k < KTL; ++k)
      wreg[g][k] = *reinterpret_cast<const short8*>(
          Wc + (size_t)(g * 512 + jtile * 16 + ln) * K + (size_t)(q * KTL + k) * 32 + lk8);

  // ---- epilogue ownership: thread = 1 row x 4 cols (one 8B h granule) ----
  const int erow  = tid >> 2;          // 0..63
  const int ecol0 = (tid & 3) << 2;    // 0,4,8,12
  const int ej    = (jtile << 4) + ecol0;
  const int egr   = base_m + erow;
  f32x4 bR, bZ, bNI, bNH;
  #pragma unroll
  for (int c = 0; c < 4; ++c){
    bR[c]  = bias4[ej + c];
    bZ[c]  = bias4[512 + ej + c];
    bNI[c] = bias4[1024 + ej + c];
    bNH[c] = bias4[1536 + ej + c];
  }

  for (int t = 0; t < T; ++t){
    // ---- sync: own group (peers done with step t-1) + producer data ----
    if (wv == 0){
      const unsigned own_t  = round0 + (unsigned)t;
      const unsigned prod_t = prod0 + (unsigned)t + 1u;
      const unsigned* pofs = own_flags + (lane & 7) * 4;
      const unsigned* ppfs = prod_flags ? (prod_flags + (lane & 7) * 4) : nullptr;
      for (;;){
        i32x4 f = load_flags16(pofs);
        bool ok = (unsigned)f.x >= own_t && (unsigned)f.y >= own_t &&
                  (unsigned)f.z >= own_t && (unsigned)f.w >= own_t;
        if (ppfs){
          i32x4 g = load_flags16(ppfs);
          ok = ok && (unsigned)g.x >= prod_t && (unsigned)g.y >= prod_t &&
                     (unsigned)g.z >= prod_t && (unsigned)g.w >= prod_t;
        }
        if (__all(ok)) break;
        __builtin_amdgcn_s_sleep(1);
      }
    }
    __syncthreads();

    const unsigned short* Hin  = (t & 1) ? hb1 : hb0;
    unsigned short*       Hout = (t & 1) ? hb0 : hb1;
    const unsigned short* Xt   = Xbase + (size_t)t * x_ts;

    // ---- stage h tile to LDS (coherence-point 16B loads) ----
    stage_tile_coh(Hin + ((size_t)base_m << 9), hA, tid);
    __syncthreads();

    // ---- MFMA K-loop: this wave's K-quarter, all 4 gates ----
    f32x4 acc[4][4];
    #pragma unroll
    for (int g = 0; g < 4; ++g)
      #pragma unroll
      for (int mt = 0; mt < 4; ++mt) acc[g][mt] = (f32x4){0.f, 0.f, 0.f, 0.f};

    #pragma unroll
    for (int k = 0; k < KTL; ++k){
      const int kt = q * KTL + k;
      short8 a[4];
      if (kt < XKT){
        #pragma unroll
        for (int mt = 0; mt < 4; ++mt)
          a[mt] = *reinterpret_cast<const short8*>(
              Xt + (size_t)(base_m + mt * 16 + ln) * x_rs + kt * 32 + lk8);
      } else {
        #pragma unroll
        for (int mt = 0; mt < 4; ++mt)
          a[mt] = *reinterpret_cast<const short8*>(
              hA + (mt * 16 + ln) * HROWB + ((kt - XKT) * 32 + lk8) * 2);
      }
      #pragma unroll
      for (int g = 0; g < 4; ++g)
        #pragma unroll
        for (int mt = 0; mt < 4; ++mt)
          acc[g][mt] = __builtin_amdgcn_mfma_f32_16x16x32_bf16(a[mt], wreg[g][k], acc[g][mt], 0, 0, 0);
    }

    // ---- partial sums to gbuf[q][g][row][col] ----
    #pragma unroll
    for (int g = 0; g < 4; ++g)
      #pragma unroll
      for (int mt = 0; mt < 4; ++mt){
        const int rl = mt * 16 + ((lane >> 4) << 2);
        #pragma unroll
        for (int i = 0; i < 4; ++i)
          gbuf[((q * 4 + g) * 64 + rl + i) * GPITCH + ln] = acc[g][mt][i];
      }
    __syncthreads();

    // ---- epilogue: sum K-quarters, GRU nonlinearity; h-prev register ----
    {
      f32x4 p0 = (f32x4){0.f,0.f,0.f,0.f}, p1 = p0, p2 = p0, p3 = p0;
      #pragma unroll
      for (int qq = 0; qq < 4; ++qq){
        p0 += *reinterpret_cast<const f32x4*>(gbuf + ((qq * 4 + 0) * 64 + erow) * GPITCH + ecol0);
        p1 += *reinterpret_cast<const f32x4*>(gbuf + ((qq * 4 + 1) * 64 + erow) * GPITCH + ecol0);
        p2 += *reinterpret_cast<const f32x4*>(gbuf + ((qq * 4 + 2) * 64 + erow) * GPITCH + ecol0);
        p3 += *reinterpret_cast<const f32x4*>(gbuf + ((qq * 4 + 3) * 64 + erow) * GPITCH + ecol0);
      }
      u64 hv = *hprev;
      u64 hb = 0;
      #pragma unroll
      for (int c = 0; c < 4; ++c){
        float rr = sigm(p0[c] + bR[c]);
        float zz = sigm(p1[c] + bZ[c]);
        float nn = tanhf(p2[c] + bNI[c] + rr * (p3[c] + bNH[c]));
        float hp = bf2f((unsigned short)(hv >> (16 * c)));
        float hn = (1.0f - zz) * nn + zz * hp;
        hb |= ((u64)f2bf(hn)) << (16 * c);
      }
      *hprev = hb;
      store_coh8(Hout + ((size_t)egr << 9) + ej, hb);
      if (Ybase)
        store_coh8(Ybase + (size_t)t * (B_ * H_) + ((size_t)egr << 9) + ej, hb);
    }

    // ---- publish: drain write-through stores, then flag my slot ----
    asm volatile("s_waitcnt vmcnt(0)" ::: "memory");
    __syncthreads();
    if (tid == 0)
      __hip_atomic_store(own_flags + slot, round0 + (unsigned)t + 1u,
                         __ATOMIC_RELAXED, __HIP_MEMORY_SCOPE_AGENT);
  }
}

__global__ __launch_bounds__(256, 1)
void rnn_persistent(
    const unsigned short* __restrict__ src, const unsigned short* __restrict__ tg,
    const unsigned short* __restrict__ Wc_e0, const unsigned short* __restrict__ Wc_e1,
    const unsigned short* __restrict__ Wc_d0, const unsigned short* __restrict__ Wc_d1,
    const float* __restrict__ b_e0, const float* __restrict__ b_e1,
    const float* __restrict__ b_d0, const float* __restrict__ b_d1,
    unsigned short* h0a, unsigned short* h0b,
    unsigned short* h1a, unsigned short* h1b,
    unsigned short* y0, unsigned short* z0, unsigned short* y1,
    unsigned* flags)
{
  // h tile (64*HROWB) + gbuf [16][64][GPITCH] f32
  __shared__ __align__(16) char smem[64 * HROWB + 16 * 64 * GPITCH * 4];
  // one-time acquire: clear stale lines (poison / previous replay) from caches
  __builtin_amdgcn_fence(__ATOMIC_ACQUIRE, "agent");
  const int wg = blockIdx.x;
  const int layer = wg >> 6;
  const int gidx = wg & 63;
  const int jtile = gidx & 31, mh = gidx >> 5;
  const int wv = threadIdx.x >> 6, lane = threadIdx.x & 63;
  unsigned* own  = flags + (size_t)((layer << 1) | mh) * 64;
  unsigned* prod = flags + (size_t)mh * 64;     // layer-0 flags of same mh
  u64 hprev = 0;
  if (layer == 0){
    run_layer<24, 8>(smem, Wc_e0, b_e0, src, S_ * D_, D_, y0,
                     h0a, h0b, S_, 0u, own, jtile, nullptr, 0u, &hprev,
                     jtile, mh, wv, lane);
    run_layer<24, 8>(smem, Wc_d0, b_d0, tg, T_ * E_, E_, z0,
                     h0a, h0b, T_, 512u, own, jtile, nullptr, 0u, &hprev,
                     jtile, mh, wv, lane);
  } else {
    run_layer<32, 16>(smem, Wc_e1, b_e1, y0, H_, B_ * H_, (unsigned short*)nullptr,
                      h1a, h1b, S_, 0u, own, jtile, prod, 0u, &hprev,
                      jtile, mh, wv, lane);
    run_layer<32, 16>(smem, Wc_d1, b_d1, z0, H_, B_ * H_, y1,
                      h1a, h1b, T_, 512u, own, jtile, prod, 512u, &hprev,
                      jtile, mh, wv, lane);
  }
}

// ---------------- generic NT GEMM: C = act(A[M,K] @ W[N,K]^T + bias) ----------------
__global__ __launch_bounds__(256)
void gemm_nt(const unsigned short* __restrict__ A, const unsigned short* __restrict__ W,
             const float* __restrict__ bias,
             unsigned short* __restrict__ outB, float* __restrict__ outF,
             int M, int N, int K, int act)
{
  const int w    = threadIdx.x >> 6;
  const int lane = threadIdx.x & 63;
  const int ln   = lane & 15;
  const int lk8  = (lane >> 4) << 3;
  const int row0 = blockIdx.y * 32;
  const int col0 = blockIdx.x * 256 + w * 64;

  f32x4 acc[2][4];
  #pragma unroll
  for (int a = 0; a < 2; a++)
    #pragma unroll
    for (int g = 0; g < 4; g++) acc[a][g] = (f32x4){0.f, 0.f, 0.f, 0.f};

  const unsigned short* arow0 = A + (size_t)(row0 + ln) * K;
  const unsigned short* arow1 = A + (size_t)(row0 + 16 + ln) * K;
  const unsigned short* wrow[4];
  int ncol[4];
  #pragma unroll
  for (int nt = 0; nt < 4; ++nt){
    int n = col0 + nt * 16 + ln;
    ncol[nt] = n;
    int nc = n < N ? n : (N - 1);
    wrow[nt] = W + (size_t)nc * K;
  }

  const int nk = K >> 5;
  for (int kt = 0; kt < nk; ++kt){
    const int k = (kt << 5) + lk8;
    short8 a0 = *reinterpret_cast<const short8*>(arow0 + k);
    short8 a1 = *reinterpret_cast<const short8*>(arow1 + k);
    #pragma unroll
    for (int nt = 0; nt < 4; ++nt){
      short8 bf = *reinterpret_cast<const short8*>(wrow[nt] + k);
      acc[0][nt] = __builtin_amdgcn_mfma_f32_16x16x32_bf16(a0, bf, acc[0][nt], 0, 0, 0);
      acc[1][nt] = __builtin_amdgcn_mfma_f32_16x16x32_bf16(a1, bf, acc[1][nt], 0, 0, 0);
    }
  }

  #pragma unroll
  for (int nt = 0; nt < 4; ++nt){
    const int n = ncol[nt];
    if (n >= N) continue;
    const float bv = bias ? bias[n] : 0.0f;
    #pragma unroll
    for (int mt = 0; mt < 2; ++mt){
      const int rbase = row0 + mt * 16 + ((lane >> 4) << 2);
      #pragma unroll
      for (int reg = 0; reg < 4; ++reg){
        const int row = rbase + reg;
        if (row >= M) continue;
        float v = acc[mt][nt][reg] + bv;
        if (act == 1) v = sigm(v);
        if (outB) outB[(size_t)row * N + n] = f2bf(v);
        if (outF) outF[(size_t)row * N + n] = v;
      }
    }
  }
}

// ---------------- pooling + loss ----------------

// y1 layout: [T][B][H]
__global__ void pool_kernel(const unsigned short* __restrict__ y1, const int* __restrict__ lengths,
                            unsigned short* __restrict__ pooled){
  int i = blockIdx.x * blockDim.x + threadIdx.x;
  if (i >= B_ * H_) return;
  int b = i >> 9;              // H_=512
  int j = i & (H_ - 1);
  int len = lengths[b]; if (len > T_) len = T_;
  float s = 0.0f;
  for (int t = 0; t < len; ++t) s += bf2f(y1[((size_t)t * B_ + b) * H_ + j]);
  pooled[i] = f2bf(s);
}

__global__ void loss_kernel(const float* __restrict__ scores, float* __restrict__ out){
  __shared__ float wsum[4];
  const int w = threadIdx.x >> 6;
  const int lane = threadIdx.x & 63;
  float acc = 0.0f;
  for (int b = w; b < B_; b += 4){
    const float* row = scores + (size_t)b * V_;
    float vals[16];
    float mx = -1e30f;
    #pragma unroll
    for (int i = 0; i < 16; ++i){
      int c = lane + i * 64;
      vals[i] = (c < V_) ? row[c] : -1e30f;
      mx = fmaxf(mx, vals[i]);
    }
    #pragma unroll
    for (int off = 32; off; off >>= 1) mx = fmaxf(mx, __shfl_xor(mx, off));
    float se = 0.0f;
    #pragma unroll
    for (int i = 0; i < 16; ++i){
      int c = lane + i * 64;
      if (c < V_) se += expf(vals[i] - mx);
    }
    #pragma unroll
    for (int off = 32; off; off >>= 1) se += __shfl_xor(se, off);
    float logp = row[END_] - (mx + logf(se));
    acc += logp;
  }
  if (lane == 0) wsum[w] = acc;
  __syncthreads();
  if (threadIdx.x == 0){
    out[0] = -(wsum[0] + wsum[1] + wsum[2] + wsum[3]) / (float)B_;
  }
}

// ---------------- host orchestration ----------------

extern "C" void kernel_launch(void* const* d_in, const int* in_sizes, int n_in,
                              void* d_out, int out_size, void* d_ws, size_t ws_size,
                              hipStream_t stream) {
  const float* source   = (const float*)d_in[0];
  const int*   tgt_ids  = (const int*)  d_in[1];
  const int*   lengths  = (const int*)  d_in[2];
  const float* emb      = (const float*)d_in[3];
  const float* eWih0 = (const float*)d_in[4],  *eWhh0 = (const float*)d_in[5];
  const float* ebih0 = (const float*)d_in[6],  *ebhh0 = (const float*)d_in[7];
  const float* eWih1 = (const float*)d_in[8],  *eWhh1 = (const float*)d_in[9];
  const float* ebih1 = (const float*)d_in[10], *ebhh1 = (const float*)d_in[11];
  const float* dWih0 = (const float*)d_in[12], *dWhh0 = (const float*)d_in[13];
  const float* dbih0 = (const float*)d_in[14], *dbhh0 = (const float*)d_in[15];
  const float* dWih1 = (const float*)d_in[16], *dWhh1 = (const float*)d_in[17];
  const float* dbih1 = (const float*)d_in[18], *dbhh1 = (const float*)d_in[19];
  const float* fcW1 = (const float*)d_in[20], *fcb1 = (const float*)d_in[21];
  const float* fcW2 = (const float*)d_in[22], *fcb2 = (const float*)d_in[23];
  const float* fcW3 = (const float*)d_in[24], *fcb3 = (const float*)d_in[25];

  char* p = (char*)d_ws;
  auto alloc = [&](size_t bytes) -> void* {
    void* r = (void*)p;
    p += (bytes + 255) & ~(size_t)255;
    return r;
  };

  unsigned short* src_bf = (unsigned short*)alloc((size_t)B_ * S_ * D_ * 2);
  unsigned short* tg_bf  = (unsigned short*)alloc((size_t)B_ * T_ * E_ * 2);
  unsigned short* y0_bf  = (unsigned short*)alloc((size_t)S_ * B_ * H_ * 2);  // [t][b][h]
  unsigned short* z0d    = (unsigned short*)alloc((size_t)T_ * B_ * H_ * 2);  // [t][b][h]
  unsigned short* y1d    = (unsigned short*)alloc((size_t)T_ * B_ * H_ * 2);  // [t][b][h]
  unsigned short* h0a = (unsigned short*)alloc((size_t)B_ * H_ * 2);
  unsigned short* h0b = (unsigned short*)alloc((size_t)B_ * H_ * 2);
  unsigned short* h1a = (unsigned short*)alloc((size_t)B_ * H_ * 2);
  unsigned short* h1b = (unsigned short*)alloc((size_t)B_ * H_ * 2);
  unsigned short* Wc_e0 = (unsigned short*)alloc((size_t)2048 * 768  * 2);
  unsigned short* Wc_e1 = (unsigned short*)alloc((size_t)2048 * 1024 * 2);
  unsigned short* Wc_d0 = (unsigned short*)alloc((size_t)2048 * 768  * 2);
  unsigned short* Wc_d1 = (unsigned short*)alloc((size_t)2048 * 1024 * 2);
  float* bias_e0 = (float*)alloc(2048 * 4);
  float* bias_e1 = (float*)alloc(2048 * 4);
  float* bias_d0 = (float*)alloc(2048 * 4);
  float* bias_d1 = (float*)alloc(2048 * 4);
  unsigned short* fcW1b = (unsigned short*)alloc((size_t)2560 * 512  * 2);
  unsigned short* fcW2b = (unsigned short*)alloc((size_t)1024 * 2560 * 2);
  unsigned short* fcW3b = (unsigned short*)alloc((size_t)V_ * 1024 * 2);
  unsigned short* pooled = (unsigned short*)alloc((size_t)B_ * H_ * 2);
  unsigned short* x1_bf  = (unsigned short*)alloc((size_t)B_ * 2560 * 2);
  unsigned short* x2_bf  = (unsigned short*)alloc((size_t)B_ * 1024 * 2);
  float* scores = (float*)alloc((size_t)B_ * V_ * 4);
  unsigned* flags = (unsigned*)alloc(4 * 64 * 4);   // 4 groups x 64 u32 (256B stride)

  // --- setup / conversions ---
  f2bf_kernel<<<8192, 256, 0, stream>>>(source, src_bf, B_ * S_ * D_);
  embed_kernel<<<(B_ * T_ * E_ + 255) / 256, 256, 0, stream>>>(emb, tgt_ids, tg_bf);
  build_wcat<<<2048, 256, 0, stream>>>(eWih0, eWhh0, Wc_e0, D_);
  build_wcat<<<2048, 256, 0, stream>>>(eWih1, eWhh1, Wc_e1, H_);
  build_wcat<<<2048, 256, 0, stream>>>(dWih0, dWhh0, Wc_d0, E_);
  build_wcat<<<2048, 256, 0, stream>>>(dWih1, dWhh1, Wc_d1, H_);
  build_bias<<<2, 256, 0, stream>>>(ebih0, ebhh0, bias_e0);
  build_bias<<<2, 256, 0, stream>>>(ebih1, ebhh1, bias_e1);
  build_bias<<<2, 256, 0, stream>>>(dbih0, dbhh0, bias_d0);
  build_bias<<<2, 256, 0, stream>>>(dbih1, dbhh1, bias_d1);
  f2bf_kernel<<<4096, 256, 0, stream>>>(fcW1, fcW1b, 2560 * 512);
  f2bf_kernel<<<4096, 256, 0, stream>>>(fcW2, fcW2b, 1024 * 2560);
  f2bf_kernel<<<4096, 256, 0, stream>>>(fcW3, fcW3b, V_ * 1024);

  hipMemsetAsync(h0a, 0, (size_t)B_ * H_ * 2, stream);
  hipMemsetAsync(h0b, 0, (size_t)B_ * H_ * 2, stream);
  hipMemsetAsync(h1a, 0, (size_t)B_ * H_ * 2, stream);
  hipMemsetAsync(h1b, 0, (size_t)B_ * H_ * 2, stream);
  hipMemsetAsync(flags, 0, 4 * 64 * 4, stream);

  // --- persistent RNN: all 4 GRU layers ---
  rnn_persistent<<<NWG_TOTAL, 256, 0, stream>>>(
      src_bf, tg_bf, Wc_e0, Wc_e1, Wc_d0, Wc_d1,
      bias_e0, bias_e1, bias_d0, bias_d1,
      h0a, h0b, h1a, h1b, y0_bf, z0d, y1d, flags);

  // --- masked time pooling ---
  pool_kernel<<<(B_ * H_ + 255) / 256, 256, 0, stream>>>(y1d, lengths, pooled);

  // --- FC chain ---
  {
    dim3 g1((2560 + 255) / 256, B_ / 32);
    gemm_nt<<<g1, 256, 0, stream>>>(pooled, fcW1b, fcb1, x1_bf, (float*)nullptr,
                                    B_, 2560, 512, 0);
    dim3 g2((1024 + 255) / 256, B_ / 32);
    gemm_nt<<<g2, 256, 0, stream>>>(x1_bf, fcW2b, fcb2, x2_bf, (float*)nullptr,
                                    B_, 1024, 2560, 0);
    dim3 g3((V_ + 255) / 256, B_ / 32);
    gemm_nt<<<g3, 256, 0, stream>>>(x2_bf, fcW3b, fcb3, (unsigned short*)nullptr, scores,
                                    B_, V_, 1024, 1);
  }

  // --- loss ---
  loss_kernel<<<1, 256, 0, stream>>>(scores, (float*)d_out);
}